// Round 2
// baseline (2918.142 us; speedup 1.0000x reference)
//
#include <hip/hip_runtime.h>
#include <hip/hip_bf16.h>

#define BB 16
#define LL 512
#define DD 512
#define NHH 8
#define HDD 64
#define TT 17

// ---------------- embedding gather: e[b,l,d] = emb[tok[b,l], d] ----------------
__global__ void embed_kernel(const int* __restrict__ tokens, const float* __restrict__ emb,
                             float* __restrict__ e, int total){
  int i = blockIdx.x*blockDim.x + threadIdx.x;
  if (i < total) {
    int t = tokens[i >> 9];     // i / 512
    int d = i & 511;
    e[i] = emb[(size_t)t*DD + d];
  }
}

// ---------------- s[b,d] = mean_l e[b,l,d] ----------------
__global__ void mean_kernel(const float* __restrict__ e, float* __restrict__ s){
  int i = blockIdx.x*blockDim.x + threadIdx.x; // 0..B*D
  int b = i >> 9, d = i & 511;
  const float* p = e + (size_t)b*LL*DD + d;
  float acc = 0.f;
  for (int l = 0; l < LL; l++) acc += p[(size_t)l*DD];
  s[(size_t)b*DD + d] = acc * (1.0f/LL);
}

// ---------------- C[M,N] = A[M,512] @ W[512,N] + bias[N] ----------------
// block 16x16 threads, 64x64 tile, 4x4 microtile, K-tile 16
__global__ void gemm_bias(const float* __restrict__ A, const float* __restrict__ W,
                          const float* __restrict__ bias, float* __restrict__ C,
                          int M, int N){
  const int K = 512;
  __shared__ float As[64][17];
  __shared__ float Bs[16][64];
  int tx = threadIdx.x, ty = threadIdx.y;
  int tid = ty*16 + tx;
  int bm = blockIdx.y*64, bn = blockIdx.x*64;
  float acc[4][4] = {{0.f}};
  for (int k0 = 0; k0 < K; k0 += 16){
    for (int i = tid; i < 1024; i += 256){
      int mm = i >> 4, kk = i & 15;
      int gm = bm + mm;
      As[mm][kk] = (gm < M) ? A[(size_t)gm*K + k0 + kk] : 0.f;
    }
    for (int i = tid; i < 1024; i += 256){
      int kk = i >> 6, nn = i & 63;
      int gn = bn + nn;
      Bs[kk][nn] = (gn < N) ? W[(size_t)(k0+kk)*N + gn] : 0.f;
    }
    __syncthreads();
    #pragma unroll
    for (int kk = 0; kk < 16; kk++){
      float a[4], bb[4];
      #pragma unroll
      for (int i = 0; i < 4; i++) a[i] = As[ty*4+i][kk];
      #pragma unroll
      for (int j = 0; j < 4; j++) bb[j] = Bs[kk][tx*4+j];
      #pragma unroll
      for (int i = 0; i < 4; i++)
        #pragma unroll
        for (int j = 0; j < 4; j++) acc[i][j] += a[i]*bb[j];
    }
    __syncthreads();
  }
  for (int i = 0; i < 4; i++){
    int gm = bm + ty*4 + i;
    if (gm >= M) continue;
    for (int j = 0; j < 4; j++){
      int gn = bn + tx*4 + j;
      if (gn >= N) continue;
      C[(size_t)gm*N + gn] = acc[i][j] + bias[gn];
    }
  }
}

// ---------------- sat attention: 5 keys per (token, head); one wave per (token,head) ----------------
__global__ void sat_attn(const float* __restrict__ Qh, const float* __restrict__ Kh,
                         const float* __restrict__ Ke, const float* __restrict__ Ks,
                         const float* __restrict__ Vh, const float* __restrict__ Ve,
                         const float* __restrict__ Vs, float* __restrict__ Aout){
  int gw = blockIdx.x*(blockDim.x >> 6) + (threadIdx.x >> 6);
  int lane = threadIdx.x & 63;
  int hh = gw & (NHH-1);
  int t  = gw >> 3;            // flat token index b*L + l
  int b = t >> 9, l = t & 511;
  int base = hh*HDD + lane;
  float q = Qh[(size_t)t*DD + base];
  int t0 = (b << 9) | ((l + 1) & 511);        // h_last = roll(h,-1)
  int t2 = (b << 9) | (l == 0 ? 511 : 0);     // h_next
  float k[5];
  k[0] = Kh[(size_t)t0*DD + base];
  k[1] = Kh[(size_t)t *DD + base];
  k[2] = Kh[(size_t)t2*DD + base];
  k[3] = Ke[(size_t)t *DD + base];
  k[4] = Ks[(size_t)b *DD + base];
  float sc[5];
  #pragma unroll
  for (int j = 0; j < 5; j++){
    float v = q * k[j];
    #pragma unroll
    for (int off = 32; off; off >>= 1) v += __shfl_xor(v, off, 64);
    sc[j] = v * 0.125f; // 1/sqrt(64)
  }
  float m = fmaxf(fmaxf(fmaxf(sc[0],sc[1]), fmaxf(sc[2],sc[3])), sc[4]);
  float p[5], den = 0.f;
  #pragma unroll
  for (int j = 0; j < 5; j++){ p[j] = expf(sc[j]-m); den += p[j]; }
  float inv = 1.0f/den;
  float v0 = Vh[(size_t)t0*DD + base];
  float v1 = Vh[(size_t)t *DD + base];
  float v2 = Vh[(size_t)t2*DD + base];
  float v3 = Ve[(size_t)t *DD + base];
  float v4 = Vs[(size_t)b *DD + base];
  Aout[(size_t)t*DD + base] = (p[0]*v0 + p[1]*v1 + p[2]*v2 + p[3]*v3 + p[4]*v4) * inv;
}

// ---------------- rel attention: 513 keys per (batch, head); one wave per block ----------------
__global__ void rel_attn(const float* __restrict__ q, const float* __restrict__ Ks,
                         const float* __restrict__ Kh, const float* __restrict__ Vs,
                         const float* __restrict__ Vh, float* __restrict__ ctx){
  int gw = blockIdx.x;
  int lane = threadIdx.x;
  int b = gw >> 3, hh = gw & 7;
  int base = hh*HDD + lane;
  float qd = q[(size_t)b*DD + base];
  // pass 1: max score
  float m = -1e30f;
  for (int j = 0; j <= LL; j++){
    float kd = (j == 0) ? Ks[(size_t)b*DD + base]
                        : Kh[((size_t)(b*LL + j - 1))*DD + base];
    float v = qd * kd;
    #pragma unroll
    for (int off = 32; off; off >>= 1) v += __shfl_xor(v, off, 64);
    m = fmaxf(m, v * 0.125f);
  }
  // pass 2: accumulate
  float den = 0.f, acc = 0.f;
  for (int j = 0; j <= LL; j++){
    float kd, vd;
    if (j == 0){ kd = Ks[(size_t)b*DD + base]; vd = Vs[(size_t)b*DD + base]; }
    else { size_t r = ((size_t)(b*LL + j - 1))*DD + base; kd = Kh[r]; vd = Vh[r]; }
    float v = qd * kd;
    #pragma unroll
    for (int off = 32; off; off >>= 1) v += __shfl_xor(v, off, 64);
    float pj = expf(v * 0.125f - m);
    den += pj; acc += pj * vd;
  }
  ctx[(size_t)b*DD + base] = acc / den;
}

// ---------------- y = ln_w * norm(relu(x)) + ln_b, row-wise over D=512 ----------------
__global__ void relu_ln(const float* __restrict__ X, const float* __restrict__ w,
                        const float* __restrict__ bn, float* __restrict__ Y){
  int row = blockIdx.x;
  int tid = threadIdx.x; // 256
  __shared__ float red[256];
  const float* x = X + (size_t)row*DD;
  float v0 = fmaxf(x[tid], 0.f), v1 = fmaxf(x[tid+256], 0.f);
  red[tid] = v0 + v1;
  __syncthreads();
  for (int st = 128; st; st >>= 1){ if (tid < st) red[tid] += red[tid+st]; __syncthreads(); }
  float u = red[0] * (1.0f/DD);
  __syncthreads();
  float d0 = v0 - u, d1 = v1 - u;
  red[tid] = d0*d0 + d1*d1;
  __syncthreads();
  for (int st = 128; st; st >>= 1){ if (tid < st) red[tid] += red[tid+st]; __syncthreads(); }
  float var = red[0] * (1.0f/DD);
  float inv = rsqrtf(var + 1e-12f);
  Y[(size_t)row*DD + tid]       = w[tid]    *d0*inv + bn[tid];
  Y[(size_t)row*DD + tid + 256] = w[tid+256]*d1*inv + bn[tid+256];
}

extern "C" void kernel_launch(void* const* d_in, const int* in_sizes, int n_in,
                              void* d_out, int out_size, void* d_ws, size_t ws_size,
                              hipStream_t stream) {
  const int*   tokens  = (const int*)  d_in[0];
  const float* emb     = (const float*)d_in[4];
  const float* sat_qw  = (const float*)d_in[5];
  const float* sat_qb  = (const float*)d_in[6];
  const float* sat_kw  = (const float*)d_in[7];
  const float* sat_kb  = (const float*)d_in[8];
  const float* sat_vw  = (const float*)d_in[9];
  const float* sat_vb  = (const float*)d_in[10];
  const float* sat_ow  = (const float*)d_in[11];
  const float* sat_ob  = (const float*)d_in[12];
  const float* rel_qw  = (const float*)d_in[13];
  const float* rel_qb  = (const float*)d_in[14];
  const float* rel_kw  = (const float*)d_in[15];
  const float* rel_kb  = (const float*)d_in[16];
  const float* rel_vw  = (const float*)d_in[17];
  const float* rel_vb  = (const float*)d_in[18];
  const float* rel_ow  = (const float*)d_in[19];
  const float* rel_ob  = (const float*)d_in[20];
  const float* ln_sat_w= (const float*)d_in[21];
  const float* ln_sat_b= (const float*)d_in[22];
  const float* ln_rel_w= (const float*)d_in[23];
  const float* ln_rel_b= (const float*)d_in[24];
  const float* ofc_w   = (const float*)d_in[25];
  const float* ofc_b   = (const float*)d_in[26];

  float* ws = (float*)d_ws;
  const size_t BIG = (size_t)BB*LL*DD; // 4,194,304 floats
  float* e  = ws;
  float* h  = ws + 1*BIG;
  float* Ke = ws + 2*BIG;
  float* Ve = ws + 3*BIG;
  float* b4 = ws + 4*BIG;  // Qh / out-proj tmp
  float* b5 = ws + 5*BIG;  // Kh / rel Kh
  float* b6 = ws + 6*BIG;  // Vh / rel Vh
  float* b7 = ws + 7*BIG;  // sat ctx / logits
  float* sm = ws + 8*BIG;
  const int SB = BB*DD;    // 8192
  float* s   = sm + 0*SB;
  float* Ks  = sm + 1*SB;
  float* Vs  = sm + 2*SB;
  float* qr  = sm + 3*SB;
  float* Ksr = sm + 4*SB;
  float* Vsr = sm + 5*SB;
  float* cr  = sm + 6*SB;
  float* rr  = sm + 7*SB;

  dim3 blk(16,16);
  dim3 gBig(8, 128);  // N=512, M=8192
  dim3 gSm (8, 1);    // N=512, M=16
  dim3 gLg (1, 128);  // N=17,  M=8192

  int total = BB*LL*DD;
  embed_kernel<<<(total+255)/256, 256, 0, stream>>>(tokens, emb, e, total);
  mean_kernel<<<(BB*DD)/256, 256, 0, stream>>>(e, s);

  // e is constant across cycles -> K/V of the 'e' context row computed once
  gemm_bias<<<gBig, blk, 0, stream>>>(e, sat_kw, sat_kb, Ke, BB*LL, DD);
  gemm_bias<<<gBig, blk, 0, stream>>>(e, sat_vw, sat_vb, Ve, BB*LL, DD);

  for (int c = 0; c < 2; c++){
    const float* hc = (c == 0) ? e : h;
    // sat projections of h (h_last/h/h_next all index into these)
    gemm_bias<<<gBig, blk, 0, stream>>>(hc, sat_qw, sat_qb, b4, BB*LL, DD);
    gemm_bias<<<gBig, blk, 0, stream>>>(hc, sat_kw, sat_kb, b5, BB*LL, DD);
    gemm_bias<<<gBig, blk, 0, stream>>>(hc, sat_vw, sat_vb, b6, BB*LL, DD);
    gemm_bias<<<gSm,  blk, 0, stream>>>(s,  sat_kw, sat_kb, Ks, BB, DD);
    gemm_bias<<<gSm,  blk, 0, stream>>>(s,  sat_vw, sat_vb, Vs, BB, DD);
    sat_attn<<<BB*LL*NHH/4, 256, 0, stream>>>(b4, b5, Ke, Ks, b6, Ve, Vs, b7);
    gemm_bias<<<gBig, blk, 0, stream>>>(b7, sat_ow, sat_ob, b4, BB*LL, DD);
    relu_ln<<<BB*LL, 256, 0, stream>>>(b4, ln_sat_w, ln_sat_b, h);
    // rel attention: query s, keys = [s; h]
    gemm_bias<<<gSm,  blk, 0, stream>>>(s, rel_qw, rel_qb, qr,  BB, DD);
    gemm_bias<<<gSm,  blk, 0, stream>>>(s, rel_kw, rel_kb, Ksr, BB, DD);
    gemm_bias<<<gSm,  blk, 0, stream>>>(s, rel_vw, rel_vb, Vsr, BB, DD);
    gemm_bias<<<gBig, blk, 0, stream>>>(h, rel_kw, rel_kb, b5, BB*LL, DD);
    gemm_bias<<<gBig, blk, 0, stream>>>(h, rel_vw, rel_vb, b6, BB*LL, DD);
    rel_attn<<<BB*NHH, 64, 0, stream>>>(qr, Ksr, b5, Vsr, b6, cr);
    gemm_bias<<<gSm,  blk, 0, stream>>>(cr, rel_ow, rel_ob, rr, BB, DD);
    relu_ln<<<BB, 256, 0, stream>>>(rr, ln_rel_w, ln_rel_b, s);
  }

  // logits = h @ ofc_w + ofc_b  (written straight to d_out as fp32)
  gemm_bias<<<gLg, blk, 0, stream>>>(h, ofc_w, ofc_b, (float*)d_out, BB*LL, TT);
}

// Round 3
// 999.872 us; speedup vs baseline: 2.9185x; 2.9185x over previous
//
#include <hip/hip_runtime.h>
#include <hip/hip_bf16.h>

typedef __hip_bfloat16 bf16;

#define BB 16
#define LL 512
#define DD 512
#define NHH 8
#define HDD 64
#define TT 17
#define MM (BB*LL)   // 8192 rows

typedef __attribute__((ext_vector_type(8))) short bfrag;   // 8 bf16
typedef __attribute__((ext_vector_type(4))) float ffrag;   // 4 fp32

static __device__ __forceinline__ void gld16(const void* g, void* l){
  __builtin_amdgcn_global_load_lds((const __attribute__((address_space(1))) void*)g,
                                   (__attribute__((address_space(3))) void*)l, 16, 0, 0);
}

// ---------------- embedding gather (fp32 + bf16 shadow) ----------------
__global__ void embed_kernel(const int* __restrict__ tokens, const float* __restrict__ emb,
                             float* __restrict__ e, bf16* __restrict__ ebf, int total){
  int i = blockIdx.x*blockDim.x + threadIdx.x;
  if (i < total) {
    int t = tokens[i >> 9];
    int d = i & 511;
    float v = emb[(size_t)t*DD + d];
    e[i] = v;
    ebf[i] = __float2bfloat16(v);
  }
}

// ---------------- s[b,d] = mean_l e[b,l,d] ----------------
__global__ void mean_kernel(const float* __restrict__ e, float* __restrict__ s){
  int i = blockIdx.x*blockDim.x + threadIdx.x;
  int b = i >> 9, d = i & 511;
  const float* p = e + (size_t)b*LL*DD + d;
  float acc = 0.f;
  for (int l = 0; l < LL; l++) acc += p[(size_t)l*DD];
  s[(size_t)b*DD + d] = acc * (1.0f/LL);
}

// ---------------- W[512][512] fp32 -> Wt[512][512] bf16 (transposed) ----------------
__global__ void transpose_bf(const float* __restrict__ in, bf16* __restrict__ out){
  __shared__ float tile[32][33];
  int tx = threadIdx.x, ty = threadIdx.y;       // 32 x 8
  int bx = blockIdx.x*32, by = blockIdx.y*32;
  #pragma unroll
  for (int j = 0; j < 32; j += 8)
    tile[ty + j][tx] = in[(size_t)(by + ty + j)*DD + bx + tx];
  __syncthreads();
  #pragma unroll
  for (int j = 0; j < 32; j += 8)
    out[(size_t)(bx + ty + j)*DD + by + tx] = __float2bfloat16(tile[tx][ty + j]);
}

// ---------------- MFMA GEMM: C[M,N] = A[M,512](bf16) @ Wt[N,512]^T(bf16) + bias ----------------
// 128x128 tile, BK=32, 256 threads (4 waves), 4x4 16x16x32 frags per wave
__global__ __launch_bounds__(256)
void gemm_mfma(const bf16* __restrict__ A, const bf16* __restrict__ Wt,
               const float* __restrict__ b0, const float* __restrict__ b1,
               const float* __restrict__ b2, float* __restrict__ C, int N){
  const int K = 512;
  __shared__ bf16 As[128*32];
  __shared__ bf16 Bs[128*32];
  int t = threadIdx.x;
  int wave = t >> 6, lane = t & 63;
  int bm = blockIdx.y * 128, bn = blockIdx.x * 128;
  int wm = (wave & 1) * 64, wn = (wave >> 1) * 64;
  ffrag acc[4][4];
  #pragma unroll
  for (int i = 0; i < 4; i++)
    #pragma unroll
    for (int j = 0; j < 4; j++) acc[i][j] = (ffrag){0.f,0.f,0.f,0.f};

  int srow = t >> 2;            // 0..63
  int scol = (t & 3) * 8;
  const bf16* gA = A  + (size_t)(bm + srow)*K + scol;
  const bf16* gB = Wt + (size_t)(bn + srow)*K + scol;
  char* lA = (char*)As + 16*t;
  char* lB = (char*)Bs + 16*t;
  int q = lane >> 4, r = lane & 15;

  for (int k0 = 0; k0 < K; k0 += 32){
    gld16(gA + k0,          lA);
    gld16(gA + 64*K + k0,   lA + 4096);
    gld16(gB + k0,          lB);
    gld16(gB + 64*K + k0,   lB + 4096);
    __syncthreads();
    bfrag af[4], bfv[4];
    #pragma unroll
    for (int i = 0; i < 4; i++){
      af[i]  = *(const bfrag*)(As + (wm + i*16 + r)*32 + q*8);
      bfv[i] = *(const bfrag*)(Bs + (wn + i*16 + r)*32 + q*8);
    }
    #pragma unroll
    for (int i = 0; i < 4; i++)
      #pragma unroll
      for (int j = 0; j < 4; j++)
        acc[i][j] = __builtin_amdgcn_mfma_f32_16x16x32_bf16(af[i], bfv[j], acc[i][j], 0, 0, 0);
    __syncthreads();
  }
  // C/D layout: col = lane&15, row = (lane>>4)*4 + reg
  #pragma unroll
  for (int i = 0; i < 4; i++){
    #pragma unroll
    for (int j = 0; j < 4; j++){
      int row = bm + wm + i*16 + q*4;
      int col = bn + wn + j*16 + r;
      const float* bp = (col < 512) ? b0 : (col < 1024) ? b1 : b2;
      float bias = bp[col & 511];
      #pragma unroll
      for (int g = 0; g < 4; g++)
        C[(size_t)(row + g)*N + col] = acc[i][j][g] + bias;
    }
  }
}

// ---------------- small GEMM: C[16,NW-slice] = s[16,512] @ W[512,NW] + b ----------------
__global__ __launch_bounds__(256)
void small_gemm(const float* __restrict__ A, const float* __restrict__ W,
                const float* __restrict__ bias, float* __restrict__ C,
                int NW, int ldc){
  __shared__ float sL[16*512];
  int t = threadIdx.x;
  for (int i = t; i < 16*512; i += 256) sL[i] = A[i];
  __syncthreads();
  int n = blockIdx.x*64 + (t & 63);
  int mg = t >> 6;                 // 0..3, 4 rows each
  float acc0=0.f, acc1=0.f, acc2=0.f, acc3=0.f;
  const float* s0 = sL + (mg*4+0)*512;
  const float* s1 = sL + (mg*4+1)*512;
  const float* s2 = sL + (mg*4+2)*512;
  const float* s3 = sL + (mg*4+3)*512;
  for (int k = 0; k < 512; k += 4){
    float w0 = W[(size_t)(k+0)*NW + n];
    float w1 = W[(size_t)(k+1)*NW + n];
    float w2 = W[(size_t)(k+2)*NW + n];
    float w3 = W[(size_t)(k+3)*NW + n];
    acc0 += s0[k]*w0 + s0[k+1]*w1 + s0[k+2]*w2 + s0[k+3]*w3;
    acc1 += s1[k]*w0 + s1[k+1]*w1 + s1[k+2]*w2 + s1[k+3]*w3;
    acc2 += s2[k]*w0 + s2[k+1]*w1 + s2[k+2]*w2 + s2[k+3]*w3;
    acc3 += s3[k]*w0 + s3[k+1]*w1 + s3[k+2]*w2 + s3[k+3]*w3;
  }
  float bv = bias[n];
  C[(size_t)(mg*4+0)*ldc + n] = acc0 + bv;
  C[(size_t)(mg*4+1)*ldc + n] = acc1 + bv;
  C[(size_t)(mg*4+2)*ldc + n] = acc2 + bv;
  C[(size_t)(mg*4+3)*ldc + n] = acc3 + bv;
}

// ---------------- sat attention: 5 keys; one wave per (token,head); bf16 ctx out ----------------
__global__ void sat_attn(const float* __restrict__ qkv, const float* __restrict__ KeVe,
                         const float* __restrict__ KsVs, bf16* __restrict__ ctx){
  int gw = blockIdx.x*(blockDim.x >> 6) + (threadIdx.x >> 6);
  int lane = threadIdx.x & 63;
  int hh = gw & (NHH-1);
  int t  = gw >> 3;
  int b = t >> 9, l = t & 511;
  int base = hh*HDD + lane;
  float qv = qkv[(size_t)t*1536 + base];
  int t0 = (b << 9) | ((l + 1) & 511);
  int t2 = (b << 9) | (l == 0 ? 511 : 0);
  float k[5];
  k[0] = qkv [(size_t)t0*1536 + 512 + base];
  k[1] = qkv [(size_t)t *1536 + 512 + base];
  k[2] = qkv [(size_t)t2*1536 + 512 + base];
  k[3] = KeVe[(size_t)t *1024 + base];
  k[4] = KsVs[(size_t)b *1024 + base];
  float sc[5];
  #pragma unroll
  for (int j = 0; j < 5; j++){
    float v = qv * k[j];
    #pragma unroll
    for (int off = 32; off; off >>= 1) v += __shfl_xor(v, off, 64);
    sc[j] = v * 0.125f;
  }
  float m = fmaxf(fmaxf(fmaxf(sc[0],sc[1]), fmaxf(sc[2],sc[3])), sc[4]);
  float p[5], den = 0.f;
  #pragma unroll
  for (int j = 0; j < 5; j++){ p[j] = __expf(sc[j]-m); den += p[j]; }
  float inv = 1.0f/den;
  float v0 = qkv [(size_t)t0*1536 + 1024 + base];
  float v1 = qkv [(size_t)t *1536 + 1024 + base];
  float v2 = qkv [(size_t)t2*1536 + 1024 + base];
  float v3 = KeVe[(size_t)t *1024 + 512 + base];
  float v4 = KsVs[(size_t)b *1024 + 512 + base];
  float o = (p[0]*v0 + p[1]*v1 + p[2]*v2 + p[3]*v3 + p[4]*v4) * inv;
  ctx[(size_t)t*DD + base] = __float2bfloat16(o);
}

// ---------------- rel attention: block per (b,h), 256 threads ----------------
__global__ __launch_bounds__(256)
void rel_attn2(const float* __restrict__ q, const float* __restrict__ Ksr,
               const float* __restrict__ Vsr, const float* __restrict__ KV,
               float* __restrict__ ctx){
  int b = blockIdx.x >> 3, hh = blockIdx.x & 7;
  int base = hh * HDD;
  int t = threadIdx.x;
  __shared__ float sc[513];
  __shared__ __align__(16) float qs[64];
  __shared__ float red[256];
  __shared__ float part[4][64];
  if (t < 64) qs[t] = q[(size_t)b*DD + base + t];
  __syncthreads();
  for (int j = t; j < 513; j += 256){
    const float* kr = (j == 0) ? (Ksr + (size_t)b*DD + base)
                               : (KV + ((size_t)b*LL + j - 1)*1024 + base);
    float a = 0.f;
    #pragma unroll
    for (int d = 0; d < 64; d += 4){
      float4 kv4 = *(const float4*)(kr + d);
      float4 q4  = *(const float4*)(qs + d);
      a += q4.x*kv4.x + q4.y*kv4.y + q4.z*kv4.z + q4.w*kv4.w;
    }
    sc[j] = a * 0.125f;
  }
  __syncthreads();
  float mv = fmaxf(sc[t], sc[t+256]);
  if (t == 0) mv = fmaxf(mv, sc[512]);
  red[t] = mv; __syncthreads();
  for (int st = 128; st; st >>= 1){ if (t < st) red[t] = fmaxf(red[t], red[t+st]); __syncthreads(); }
  float m = red[0]; __syncthreads();
  for (int j = t; j < 513; j += 256) sc[j] = __expf(sc[j] - m);
  __syncthreads();
  float sv = sc[t] + sc[t+256];
  if (t == 0) sv += sc[512];
  red[t] = sv; __syncthreads();
  for (int st = 128; st; st >>= 1){ if (t < st) red[t] += red[t+st]; __syncthreads(); }
  float inv = 1.0f / red[0];
  int d = t & 63, c = t >> 6;
  float a = 0.f;
  for (int j = c; j < 513; j += 4){
    float vv = (j == 0) ? Vsr[(size_t)b*DD + base + d]
                        : KV[((size_t)b*LL + j - 1)*1024 + 512 + base + d];
    a += sc[j] * vv;
  }
  part[c][d] = a; __syncthreads();
  if (t < 64)
    ctx[(size_t)b*DD + base + t] = (part[0][t]+part[1][t]+part[2][t]+part[3][t]) * inv;
}

// ---------------- y = ln_w * norm(relu(x)) + ln_b (+ bf16 shadow) ----------------
__global__ void relu_ln(const float* __restrict__ X, const float* __restrict__ w,
                        const float* __restrict__ bn, float* __restrict__ Y,
                        bf16* __restrict__ Ybf){
  int row = blockIdx.x;
  int tid = threadIdx.x; // 256
  __shared__ float red[256];
  const float* x = X + (size_t)row*DD;
  float v0 = fmaxf(x[tid], 0.f), v1 = fmaxf(x[tid+256], 0.f);
  red[tid] = v0 + v1;
  __syncthreads();
  for (int st = 128; st; st >>= 1){ if (tid < st) red[tid] += red[tid+st]; __syncthreads(); }
  float u = red[0] * (1.0f/DD);
  __syncthreads();
  float d0 = v0 - u, d1 = v1 - u;
  red[tid] = d0*d0 + d1*d1;
  __syncthreads();
  for (int st = 128; st; st >>= 1){ if (tid < st) red[tid] += red[tid+st]; __syncthreads(); }
  float var = red[0] * (1.0f/DD);
  float inv = rsqrtf(var + 1e-12f);
  float y0 = w[tid]    *d0*inv + bn[tid];
  float y1 = w[tid+256]*d1*inv + bn[tid+256];
  Y[(size_t)row*DD + tid]       = y0;
  Y[(size_t)row*DD + tid + 256] = y1;
  Ybf[(size_t)row*DD + tid]       = __float2bfloat16(y0);
  Ybf[(size_t)row*DD + tid + 256] = __float2bfloat16(y1);
}

// ---------------- logits: C[8192,17] = h[8192,512] @ W[512,17] + b (fp32) ----------------
__global__ __launch_bounds__(256)
void logits_kernel(const float* __restrict__ h, const float* __restrict__ W,
                   const float* __restrict__ bias, float* __restrict__ out){
  int t = threadIdx.x;
  if (t >= 255) return;
  int m = blockIdx.x*15 + t/17;
  int n = t % 17;
  if (m >= MM) return;
  const float* hr = h + (size_t)m*DD;
  float acc = 0.f;
  for (int k = 0; k < 512; k += 4){
    float4 h4 = *(const float4*)(hr + k);
    acc += h4.x*W[(size_t)(k+0)*TT + n] + h4.y*W[(size_t)(k+1)*TT + n]
         + h4.z*W[(size_t)(k+2)*TT + n] + h4.w*W[(size_t)(k+3)*TT + n];
  }
  out[(size_t)m*TT + n] = acc + bias[n];
}

extern "C" void kernel_launch(void* const* d_in, const int* in_sizes, int n_in,
                              void* d_out, int out_size, void* d_ws, size_t ws_size,
                              hipStream_t stream) {
  const int*   tokens  = (const int*)  d_in[0];
  const float* emb     = (const float*)d_in[4];
  const float* sat_qw  = (const float*)d_in[5];
  const float* sat_qb  = (const float*)d_in[6];
  const float* sat_kw  = (const float*)d_in[7];
  const float* sat_kb  = (const float*)d_in[8];
  const float* sat_vw  = (const float*)d_in[9];
  const float* sat_vb  = (const float*)d_in[10];
  const float* sat_ow  = (const float*)d_in[11];
  const float* sat_ob  = (const float*)d_in[12];
  const float* rel_qw  = (const float*)d_in[13];
  const float* rel_qb  = (const float*)d_in[14];
  const float* rel_kw  = (const float*)d_in[15];
  const float* rel_kb  = (const float*)d_in[16];
  const float* rel_vw  = (const float*)d_in[17];
  const float* rel_vb  = (const float*)d_in[18];
  const float* rel_ow  = (const float*)d_in[19];
  const float* rel_ob  = (const float*)d_in[20];
  const float* ln_sat_w= (const float*)d_in[21];
  const float* ln_sat_b= (const float*)d_in[22];
  const float* ln_rel_w= (const float*)d_in[23];
  const float* ln_rel_b= (const float*)d_in[24];
  const float* ofc_w   = (const float*)d_in[25];
  const float* ofc_b   = (const float*)d_in[26];

  char* p = (char*)d_ws;
  auto alloc = [&](size_t bytes) -> char* {
    char* r = p; p += (bytes + 255) & ~(size_t)255; return r;
  };
  const size_t BIGB = (size_t)MM*DD*4;         // 16 MB
  float* e     = (float*)alloc(BIGB);
  float* h     = (float*)alloc(BIGB);
  bf16*  ebf   = (bf16*) alloc(BIGB/2);        // aliased later as h_bf
  float* KeVe  = (float*)alloc(2*BIGB);        // [M,1024]
  float* qkv   = (float*)alloc(3*BIGB);        // [M,1536]; aout = qkv[0:4M]; kv = qkv+4M [M,1024]
  bf16*  ctxbf = (bf16*) alloc(BIGB/2);
  bf16*  WtSat = (bf16*) alloc((size_t)1536*512*2);  // [qw;kw;vw]^T
  bf16*  WtRel = (bf16*) alloc((size_t)1024*512*2);  // [kw;vw]^T
  bf16*  WtO   = (bf16*) alloc((size_t)512*512*2);
  float* s     = (float*)alloc(BB*DD*4);
  float* KsVs  = (float*)alloc(BB*1024*4);
  float* qr    = (float*)alloc(BB*DD*4);
  float* Ksr   = (float*)alloc(BB*DD*4);
  float* Vsr   = (float*)alloc(BB*DD*4);
  float* cr    = (float*)alloc(BB*DD*4);
  float* rr    = (float*)alloc(BB*DD*4);
  bf16*  sbfd  = (bf16*) alloc(BB*DD*2);       // dummy bf16 sink for s-LN
  bf16*  hbf   = ebf;                           // reuse: e_bf dead after cycle-0 QKV
  float* aout  = qkv;                           // reuse: qkv dead after sat_attn
  float* kv    = qkv + (size_t)MM*512;          // [M,1024] inside qkv region

  dim3 tb(32, 8);
  dim3 tg(16, 16);
  int total = MM*DD;

  embed_kernel<<<(total+255)/256, 256, 0, stream>>>(tokens, emb, e, ebf, total);
  mean_kernel<<<(BB*DD)/256, 256, 0, stream>>>(e, s);

  // weight prep (transpose + bf16) — once per launch
  transpose_bf<<<tg, tb, 0, stream>>>(sat_qw, WtSat);
  transpose_bf<<<tg, tb, 0, stream>>>(sat_kw, WtSat + (size_t)512*512);
  transpose_bf<<<tg, tb, 0, stream>>>(sat_vw, WtSat + (size_t)1024*512);
  transpose_bf<<<tg, tb, 0, stream>>>(rel_kw, WtRel);
  transpose_bf<<<tg, tb, 0, stream>>>(rel_vw, WtRel + (size_t)512*512);
  transpose_bf<<<tg, tb, 0, stream>>>(sat_ow, WtO);

  // Ke|Ve = e @ [sat_kw|sat_vw] (rows 512..1535 of WtSat)
  gemm_mfma<<<dim3(8,64), 256, 0, stream>>>(ebf, WtSat + (size_t)512*512,
                                            sat_kb, sat_vb, sat_vb, KeVe, 1024);

  for (int c = 0; c < 2; c++){
    const bf16* hc = (c == 0) ? ebf : hbf;
    gemm_mfma<<<dim3(12,64), 256, 0, stream>>>(hc, WtSat, sat_qb, sat_kb, sat_vb, qkv, 1536);
    small_gemm<<<8, 256, 0, stream>>>(s, sat_kw, sat_kb, KsVs,       512, 1024);
    small_gemm<<<8, 256, 0, stream>>>(s, sat_vw, sat_vb, KsVs + 512, 512, 1024);
    sat_attn<<<MM*NHH/4, 256, 0, stream>>>(qkv, KeVe, KsVs, ctxbf);
    gemm_mfma<<<dim3(4,64), 256, 0, stream>>>(ctxbf, WtO, sat_ob, sat_ob, sat_ob, aout, 512);
    relu_ln<<<MM, 256, 0, stream>>>(aout, ln_sat_w, ln_sat_b, h, hbf);
    small_gemm<<<8, 256, 0, stream>>>(s, rel_qw, rel_qb, qr,  512, 512);
    small_gemm<<<8, 256, 0, stream>>>(s, rel_kw, rel_kb, Ksr, 512, 512);
    small_gemm<<<8, 256, 0, stream>>>(s, rel_vw, rel_vb, Vsr, 512, 512);
    gemm_mfma<<<dim3(8,64), 256, 0, stream>>>(hbf, WtRel, rel_kb, rel_vb, rel_vb, kv, 1024);
    rel_attn2<<<BB*NHH, 256, 0, stream>>>(qr, Ksr, Vsr, kv, cr);
    small_gemm<<<8, 256, 0, stream>>>(cr, rel_ow, rel_ob, rr, 512, 512);
    relu_ln<<<BB, 256, 0, stream>>>(rr, ln_rel_w, ln_rel_b, s, sbfd);
  }

  logits_kernel<<<(MM + 14)/15, 256, 0, stream>>>(h, ofc_w, ofc_b, (float*)d_out);
}

// Round 4
// 652.799 us; speedup vs baseline: 4.4702x; 1.5317x over previous
//
#include <hip/hip_runtime.h>
#include <hip/hip_bf16.h>

typedef __hip_bfloat16 bf16;

#define BB 16
#define LL 512
#define DD 512
#define NHH 8
#define HDD 64
#define TT 17
#define MM (BB*LL)   // 8192 rows

typedef __attribute__((ext_vector_type(8))) short bfrag;   // 8 bf16
typedef __attribute__((ext_vector_type(4))) float ffrag;   // 4 fp32

static __device__ __forceinline__ void gld16(const void* g, void* l){
  __builtin_amdgcn_global_load_lds((const __attribute__((address_space(1))) void*)g,
                                   (__attribute__((address_space(3))) void*)l, 16, 0, 0);
}

// ---------------- embedding gather (fp32 + bf16 shadow) ----------------
__global__ void embed_kernel(const int* __restrict__ tokens, const float* __restrict__ emb,
                             float* __restrict__ e, bf16* __restrict__ ebf, int total){
  int i = blockIdx.x*blockDim.x + threadIdx.x;
  if (i < total) {
    int t = tokens[i >> 9];
    int d = i & 511;
    float v = emb[(size_t)t*DD + d];
    e[i] = v;
    ebf[i] = __float2bfloat16(v);
  }
}

// ---------------- s[b,d] = mean_l e[b,l,d] ----------------
__global__ void mean_kernel(const float* __restrict__ e, float* __restrict__ s){
  int i = blockIdx.x*blockDim.x + threadIdx.x;
  int b = i >> 9, d = i & 511;
  const float* p = e + (size_t)b*LL*DD + d;
  float acc = 0.f;
  for (int l = 0; l < LL; l++) acc += p[(size_t)l*DD];
  s[(size_t)b*DD + d] = acc * (1.0f/LL);
}

// ---------------- W[512][512] fp32 -> Wt[512][512] bf16 (transposed) ----------------
__global__ void transpose_bf(const float* __restrict__ in, bf16* __restrict__ out){
  __shared__ float tile[32][33];
  int tx = threadIdx.x, ty = threadIdx.y;       // 32 x 8
  int bx = blockIdx.x*32, by = blockIdx.y*32;
  #pragma unroll
  for (int j = 0; j < 32; j += 8)
    tile[ty + j][tx] = in[(size_t)(by + ty + j)*DD + bx + tx];
  __syncthreads();
  #pragma unroll
  for (int j = 0; j < 32; j += 8)
    out[(size_t)(bx + ty + j)*DD + by + tx] = __float2bfloat16(tile[tx][ty + j]);
}

// ---------------- MFMA GEMM: C[M,N] = A[M,512](bf16) @ Wt[N,512]^T(bf16) + bias ----------------
// 128x128 tile, BK=32, 256 threads (4 waves), 4x4 16x16x32 frags per wave
__global__ __launch_bounds__(256)
void gemm_mfma(const bf16* __restrict__ A, const bf16* __restrict__ Wt,
               const float* __restrict__ b0, const float* __restrict__ b1,
               const float* __restrict__ b2, float* __restrict__ C, int N){
  const int K = 512;
  __shared__ bf16 As[128*32];
  __shared__ bf16 Bs[128*32];
  int t = threadIdx.x;
  int wave = t >> 6, lane = t & 63;
  int bm = blockIdx.y * 128, bn = blockIdx.x * 128;
  int wm = (wave & 1) * 64, wn = (wave >> 1) * 64;
  ffrag acc[4][4];
  #pragma unroll
  for (int i = 0; i < 4; i++)
    #pragma unroll
    for (int j = 0; j < 4; j++) acc[i][j] = (ffrag){0.f,0.f,0.f,0.f};

  int srow = t >> 2;            // 0..63
  int scol = (t & 3) * 8;
  const bf16* gA = A  + (size_t)(bm + srow)*K + scol;
  const bf16* gB = Wt + (size_t)(bn + srow)*K + scol;
  char* lA = (char*)As + 16*t;
  char* lB = (char*)Bs + 16*t;
  int q = lane >> 4, r = lane & 15;

  for (int k0 = 0; k0 < K; k0 += 32){
    gld16(gA + k0,          lA);
    gld16(gA + 64*K + k0,   lA + 4096);
    gld16(gB + k0,          lB);
    gld16(gB + 64*K + k0,   lB + 4096);
    __syncthreads();
    bfrag af[4], bfv[4];
    #pragma unroll
    for (int i = 0; i < 4; i++){
      af[i]  = *(const bfrag*)(As + (wm + i*16 + r)*32 + q*8);
      bfv[i] = *(const bfrag*)(Bs + (wn + i*16 + r)*32 + q*8);
    }
    #pragma unroll
    for (int i = 0; i < 4; i++)
      #pragma unroll
      for (int j = 0; j < 4; j++)
        acc[i][j] = __builtin_amdgcn_mfma_f32_16x16x32_bf16(af[i], bfv[j], acc[i][j], 0, 0, 0);
    __syncthreads();
  }
  // C/D layout: col = lane&15, row = (lane>>4)*4 + reg
  #pragma unroll
  for (int i = 0; i < 4; i++){
    #pragma unroll
    for (int j = 0; j < 4; j++){
      int row = bm + wm + i*16 + q*4;
      int col = bn + wn + j*16 + r;
      const float* bp = (col < 512) ? b0 : (col < 1024) ? b1 : b2;
      float bias = bp[col & 511];
      #pragma unroll
      for (int g = 0; g < 4; g++)
        C[(size_t)(row + g)*N + col] = acc[i][j][g] + bias;
    }
  }
}

// ---------------- batched s-projections: C_w[16, 512] = A[16,512] @ W_w[512,512] + b_w ----------------
// grid = nW*8 blocks; block (wi, chunk of 64 cols); 256 threads = 64 cols x 4 k-groups;
// each thread: 16 fp32 accumulators (all rows), k-slice of 128; LDS split-k reduce.
__global__ __launch_bounds__(256)
void s_proj(const float* __restrict__ A,
            const float* __restrict__ W0, const float* __restrict__ W1,
            const float* __restrict__ W2, const float* __restrict__ W3,
            const float* __restrict__ W4,
            const float* __restrict__ bias0, const float* __restrict__ bias1,
            const float* __restrict__ bias2, const float* __restrict__ bias3,
            const float* __restrict__ bias4,
            float* __restrict__ O0, float* __restrict__ O1,
            float* __restrict__ O2, float* __restrict__ O3,
            float* __restrict__ O4,
            int ldc0, int ldc1, int ldc2, int ldc3, int ldc4){
  __shared__ float part[4][64][17];
  int t = threadIdx.x;
  int n = t & 63, kg = t >> 6;
  int wi = blockIdx.x >> 3, ch = blockIdx.x & 7;
  const float* W  = (wi==0)?W0:(wi==1)?W1:(wi==2)?W2:(wi==3)?W3:W4;
  const float* bs = (wi==0)?bias0:(wi==1)?bias1:(wi==2)?bias2:(wi==3)?bias3:bias4;
  float* O  = (wi==0)?O0:(wi==1)?O1:(wi==2)?O2:(wi==3)?O3:O4;
  int ldc   = (wi==0)?ldc0:(wi==1)?ldc1:(wi==2)?ldc2:(wi==3)?ldc3:ldc4;
  int col = ch*64 + n;
  float acc[16];
  #pragma unroll
  for (int m = 0; m < 16; m++) acc[m] = 0.f;
  const float* Wp = W + (size_t)(kg*128)*512 + col;
  const float* Ap = A + kg*128;               // wave-uniform -> scalar loads
  for (int k = 0; k < 128; k++){
    float w = Wp[(size_t)k*512];
    #pragma unroll
    for (int m = 0; m < 16; m++) acc[m] = fmaf(Ap[m*512 + k], w, acc[m]);
  }
  #pragma unroll
  for (int m = 0; m < 16; m++) part[kg][n][m] = acc[m];
  __syncthreads();
  for (int o = t; o < 1024; o += 256){
    int m = o >> 6, nn = o & 63;
    float v = part[0][nn][m] + part[1][nn][m] + part[2][nn][m] + part[3][nn][m];
    O[(size_t)m*ldc + ch*64 + nn] = v + bs[ch*64 + nn];
  }
}

// ---------------- sat attention: 5 keys; one wave per (token,head); bf16 ctx out ----------------
__global__ void sat_attn(const float* __restrict__ qkv, const float* __restrict__ KeVe,
                         const float* __restrict__ KsVs, bf16* __restrict__ ctx){
  int gw = blockIdx.x*(blockDim.x >> 6) + (threadIdx.x >> 6);
  int lane = threadIdx.x & 63;
  int hh = gw & (NHH-1);
  int t  = gw >> 3;
  int b = t >> 9, l = t & 511;
  int base = hh*HDD + lane;
  float qv = qkv[(size_t)t*1536 + base];
  int t0 = (b << 9) | ((l + 1) & 511);
  int t2 = (b << 9) | (l == 0 ? 511 : 0);
  float k[5];
  k[0] = qkv [(size_t)t0*1536 + 512 + base];
  k[1] = qkv [(size_t)t *1536 + 512 + base];
  k[2] = qkv [(size_t)t2*1536 + 512 + base];
  k[3] = KeVe[(size_t)t *1024 + base];
  k[4] = KsVs[(size_t)b *1024 + base];
  float sc[5];
  #pragma unroll
  for (int j = 0; j < 5; j++){
    float v = qv * k[j];
    #pragma unroll
    for (int off = 32; off; off >>= 1) v += __shfl_xor(v, off, 64);
    sc[j] = v * 0.125f;
  }
  float m = fmaxf(fmaxf(fmaxf(sc[0],sc[1]), fmaxf(sc[2],sc[3])), sc[4]);
  float p[5], den = 0.f;
  #pragma unroll
  for (int j = 0; j < 5; j++){ p[j] = __expf(sc[j]-m); den += p[j]; }
  float inv = 1.0f/den;
  float v0 = qkv [(size_t)t0*1536 + 1024 + base];
  float v1 = qkv [(size_t)t *1536 + 1024 + base];
  float v2 = qkv [(size_t)t2*1536 + 1024 + base];
  float v3 = KeVe[(size_t)t *1024 + 512 + base];
  float v4 = KsVs[(size_t)b *1024 + 512 + base];
  float o = (p[0]*v0 + p[1]*v1 + p[2]*v2 + p[3]*v3 + p[4]*v4) * inv;
  ctx[(size_t)t*DD + base] = __float2bfloat16(o);
}

// ---------------- rel attention: block per (b,h), 256 threads ----------------
__global__ __launch_bounds__(256)
void rel_attn2(const float* __restrict__ q, const float* __restrict__ Ksr,
               const float* __restrict__ Vsr, const float* __restrict__ KV,
               float* __restrict__ ctx){
  int b = blockIdx.x >> 3, hh = blockIdx.x & 7;
  int base = hh * HDD;
  int t = threadIdx.x;
  __shared__ float sc[513];
  __shared__ __align__(16) float qs[64];
  __shared__ float red[256];
  __shared__ float part[4][64];
  if (t < 64) qs[t] = q[(size_t)b*DD + base + t];
  __syncthreads();
  for (int j = t; j < 513; j += 256){
    const float* kr = (j == 0) ? (Ksr + (size_t)b*DD + base)
                               : (KV + ((size_t)b*LL + j - 1)*1024 + base);
    float a = 0.f;
    #pragma unroll
    for (int d = 0; d < 64; d += 4){
      float4 kv4 = *(const float4*)(kr + d);
      float4 q4  = *(const float4*)(qs + d);
      a += q4.x*kv4.x + q4.y*kv4.y + q4.z*kv4.z + q4.w*kv4.w;
    }
    sc[j] = a * 0.125f;
  }
  __syncthreads();
  float mv = fmaxf(sc[t], sc[t+256]);
  if (t == 0) mv = fmaxf(mv, sc[512]);
  red[t] = mv; __syncthreads();
  for (int st = 128; st; st >>= 1){ if (t < st) red[t] = fmaxf(red[t], red[t+st]); __syncthreads(); }
  float m = red[0]; __syncthreads();
  for (int j = t; j < 513; j += 256) sc[j] = __expf(sc[j] - m);
  __syncthreads();
  float sv = sc[t] + sc[t+256];
  if (t == 0) sv += sc[512];
  red[t] = sv; __syncthreads();
  for (int st = 128; st; st >>= 1){ if (t < st) red[t] += red[t+st]; __syncthreads(); }
  float inv = 1.0f / red[0];
  int d = t & 63, c = t >> 6;
  float a = 0.f;
  for (int j = c; j < 513; j += 4){
    float vv = (j == 0) ? Vsr[(size_t)b*DD + base + d]
                        : KV[((size_t)b*LL + j - 1)*1024 + 512 + base + d];
    a += sc[j] * vv;
  }
  part[c][d] = a; __syncthreads();
  if (t < 64)
    ctx[(size_t)b*DD + base + t] = (part[0][t]+part[1][t]+part[2][t]+part[3][t]) * inv;
}

// ---------------- y = ln_w * norm(relu(x)) + ln_b (+ bf16 shadow) ----------------
__global__ void relu_ln(const float* __restrict__ X, const float* __restrict__ w,
                        const float* __restrict__ bn, float* __restrict__ Y,
                        bf16* __restrict__ Ybf){
  int row = blockIdx.x;
  int tid = threadIdx.x; // 256
  __shared__ float red[256];
  const float* x = X + (size_t)row*DD;
  float v0 = fmaxf(x[tid], 0.f), v1 = fmaxf(x[tid+256], 0.f);
  red[tid] = v0 + v1;
  __syncthreads();
  for (int st = 128; st; st >>= 1){ if (tid < st) red[tid] += red[tid+st]; __syncthreads(); }
  float u = red[0] * (1.0f/DD);
  __syncthreads();
  float d0 = v0 - u, d1 = v1 - u;
  red[tid] = d0*d0 + d1*d1;
  __syncthreads();
  for (int st = 128; st; st >>= 1){ if (tid < st) red[tid] += red[tid+st]; __syncthreads(); }
  float var = red[0] * (1.0f/DD);
  float inv = rsqrtf(var + 1e-12f);
  float y0 = w[tid]    *d0*inv + bn[tid];
  float y1 = w[tid+256]*d1*inv + bn[tid+256];
  Y[(size_t)row*DD + tid]       = y0;
  Y[(size_t)row*DD + tid + 256] = y1;
  Ybf[(size_t)row*DD + tid]       = __float2bfloat16(y0);
  Ybf[(size_t)row*DD + tid + 256] = __float2bfloat16(y1);
}

// ---------------- logits: C[8192,17] = h[8192,512] @ W[512,17] + b (fp32) ----------------
__global__ __launch_bounds__(256)
void logits_kernel(const float* __restrict__ h, const float* __restrict__ W,
                   const float* __restrict__ bias, float* __restrict__ out){
  int t = threadIdx.x;
  if (t >= 255) return;
  int m = blockIdx.x*15 + t/17;
  int n = t % 17;
  if (m >= MM) return;
  const float* hr = h + (size_t)m*DD;
  float acc = 0.f;
  for (int k = 0; k < 512; k += 4){
    float4 h4 = *(const float4*)(hr + k);
    acc += h4.x*W[(size_t)(k+0)*TT + n] + h4.y*W[(size_t)(k+1)*TT + n]
         + h4.z*W[(size_t)(k+2)*TT + n] + h4.w*W[(size_t)(k+3)*TT + n];
  }
  out[(size_t)m*TT + n] = acc + bias[n];
}

extern "C" void kernel_launch(void* const* d_in, const int* in_sizes, int n_in,
                              void* d_out, int out_size, void* d_ws, size_t ws_size,
                              hipStream_t stream) {
  const int*   tokens  = (const int*)  d_in[0];
  const float* emb     = (const float*)d_in[4];
  const float* sat_qw  = (const float*)d_in[5];
  const float* sat_qb  = (const float*)d_in[6];
  const float* sat_kw  = (const float*)d_in[7];
  const float* sat_kb  = (const float*)d_in[8];
  const float* sat_vw  = (const float*)d_in[9];
  const float* sat_vb  = (const float*)d_in[10];
  const float* sat_ow  = (const float*)d_in[11];
  const float* sat_ob  = (const float*)d_in[12];
  const float* rel_qw  = (const float*)d_in[13];
  const float* rel_qb  = (const float*)d_in[14];
  const float* rel_kw  = (const float*)d_in[15];
  const float* rel_kb  = (const float*)d_in[16];
  const float* rel_vw  = (const float*)d_in[17];
  const float* rel_vb  = (const float*)d_in[18];
  const float* rel_ow  = (const float*)d_in[19];
  const float* rel_ob  = (const float*)d_in[20];
  const float* ln_sat_w= (const float*)d_in[21];
  const float* ln_sat_b= (const float*)d_in[22];
  const float* ln_rel_w= (const float*)d_in[23];
  const float* ln_rel_b= (const float*)d_in[24];
  const float* ofc_w   = (const float*)d_in[25];
  const float* ofc_b   = (const float*)d_in[26];

  char* p = (char*)d_ws;
  auto alloc = [&](size_t bytes) -> char* {
    char* r = p; p += (bytes + 255) & ~(size_t)255; return r;
  };
  const size_t BIGB = (size_t)MM*DD*4;         // 16 MB
  float* e     = (float*)alloc(BIGB);
  float* h     = (float*)alloc(BIGB);
  bf16*  ebf   = (bf16*) alloc(BIGB/2);        // aliased later as h_bf
  float* KeVe  = (float*)alloc(2*BIGB);        // [M,1024]
  float* qkv   = (float*)alloc(3*BIGB);        // [M,1536]
  bf16*  ctxbf = (bf16*) alloc(BIGB/2);
  bf16*  WtSat = (bf16*) alloc((size_t)1536*512*2);  // [qw;kw;vw]^T
  bf16*  WtRel = (bf16*) alloc((size_t)1024*512*2);  // [kw;vw]^T
  bf16*  WtO   = (bf16*) alloc((size_t)512*512*2);
  float* s     = (float*)alloc(BB*DD*4);
  float* KsVs  = (float*)alloc(BB*1024*4);
  float* qr    = (float*)alloc(BB*DD*4);
  float* Ksr   = (float*)alloc(BB*DD*4);
  float* Vsr   = (float*)alloc(BB*DD*4);
  float* cr    = (float*)alloc(BB*DD*4);
  float* rr    = (float*)alloc(BB*DD*4);
  bf16*  sbfd  = (bf16*) alloc(BB*DD*2);       // dummy bf16 sink for s-LN
  bf16*  hbf   = ebf;                           // reuse: e_bf dead after cycle-0 QKV
  float* aout  = qkv;                           // reuse: qkv dead after sat_attn
  float* kv    = qkv + (size_t)MM*512;          // [M,1024] inside qkv region

  dim3 tb(32, 8);
  dim3 tg(16, 16);
  int total = MM*DD;

  embed_kernel<<<(total+255)/256, 256, 0, stream>>>(tokens, emb, e, ebf, total);
  mean_kernel<<<(BB*DD)/256, 256, 0, stream>>>(e, s);

  // weight prep (transpose + bf16) — once per launch
  transpose_bf<<<tg, tb, 0, stream>>>(sat_qw, WtSat);
  transpose_bf<<<tg, tb, 0, stream>>>(sat_kw, WtSat + (size_t)512*512);
  transpose_bf<<<tg, tb, 0, stream>>>(sat_vw, WtSat + (size_t)1024*512);
  transpose_bf<<<tg, tb, 0, stream>>>(rel_kw, WtRel);
  transpose_bf<<<tg, tb, 0, stream>>>(rel_vw, WtRel + (size_t)512*512);
  transpose_bf<<<tg, tb, 0, stream>>>(sat_ow, WtO);

  // Ke|Ve = e @ [sat_kw|sat_vw] (rows 512..1535 of WtSat)
  gemm_mfma<<<dim3(8,64), 256, 0, stream>>>(ebf, WtSat + (size_t)512*512,
                                            sat_kb, sat_vb, sat_vb, KeVe, 1024);

  for (int c = 0; c < 2; c++){
    const bf16* hc = (c == 0) ? ebf : hbf;
    gemm_mfma<<<dim3(12,64), 256, 0, stream>>>(hc, WtSat, sat_qb, sat_kb, sat_vb, qkv, 1536);
    // all five s-projections in one launch: sat_k, sat_v -> KsVs ; rel q/k/v -> qr/Ksr/Vsr
    s_proj<<<40, 256, 0, stream>>>(s,
        sat_kw, sat_vw, rel_qw, rel_kw, rel_vw,
        sat_kb, sat_vb, rel_qb, rel_kb, rel_vb,
        KsVs, KsVs + 512, qr, Ksr, Vsr,
        1024, 1024, 512, 512, 512);
    sat_attn<<<MM*NHH/4, 256, 0, stream>>>(qkv, KeVe, KsVs, ctxbf);
    gemm_mfma<<<dim3(4,64), 256, 0, stream>>>(ctxbf, WtO, sat_ob, sat_ob, sat_ob, aout, 512);
    relu_ln<<<MM, 256, 0, stream>>>(aout, ln_sat_w, ln_sat_b, h, hbf);
    gemm_mfma<<<dim3(8,64), 256, 0, stream>>>(hbf, WtRel, rel_kb, rel_vb, rel_vb, kv, 1024);
    rel_attn2<<<BB*NHH, 256, 0, stream>>>(qr, Ksr, Vsr, kv, cr);
    // rel out-projection: single weight through the same kernel (8 blocks)
    s_proj<<<8, 256, 0, stream>>>(cr,
        rel_ow, rel_ow, rel_ow, rel_ow, rel_ow,
        rel_ob, rel_ob, rel_ob, rel_ob, rel_ob,
        rr, rr, rr, rr, rr,
        512, 512, 512, 512, 512);
    relu_ln<<<BB, 256, 0, stream>>>(rr, ln_rel_w, ln_rel_b, s, sbfd);
  }

  logits_kernel<<<(MM + 14)/15, 256, 0, stream>>>(h, ofc_w, ofc_b, (float*)d_out);
}

// Round 6
// 577.481 us; speedup vs baseline: 5.0532x; 1.1304x over previous
//
#include <hip/hip_runtime.h>
#include <hip/hip_bf16.h>

typedef __hip_bfloat16 bf16;

#define BB 16
#define LL 512
#define DD 512
#define NHH 8
#define HDD 64
#define TT 17
#define MM (BB*LL)   // 8192 rows
#define RCH 8        // rel-attn key chunks
#define RCK 65       // keys per chunk (8*65=520 >= 513)

typedef __attribute__((ext_vector_type(8))) short bfrag;   // 8 bf16
typedef __attribute__((ext_vector_type(4))) float ffrag;   // 4 fp32

static __device__ __forceinline__ void gld16(const void* g, void* l){
  __builtin_amdgcn_global_load_lds((const __attribute__((address_space(1))) void*)g,
                                   (__attribute__((address_space(3))) void*)l, 16, 0, 0);
}

// ---------------- embedding gather (fp32 + bf16 shadow) ----------------
__global__ void embed_kernel(const int* __restrict__ tokens, const float* __restrict__ emb,
                             float* __restrict__ e, bf16* __restrict__ ebf, int total){
  int i = blockIdx.x*blockDim.x + threadIdx.x;
  if (i < total) {
    int t = tokens[i >> 9];
    int d = i & 511;
    float v = emb[(size_t)t*DD + d];
    e[i] = v;
    ebf[i] = __float2bfloat16(v);
  }
}

// ---------------- s[b,d] = mean_l e[b,l,d] ----------------
__global__ void mean_kernel(const float* __restrict__ e, float* __restrict__ s){
  int i = blockIdx.x*blockDim.x + threadIdx.x;
  int b = i >> 9, d = i & 511;
  const float* p = e + (size_t)b*LL*DD + d;
  float acc = 0.f;
  for (int l = 0; l < LL; l++) acc += p[(size_t)l*DD];
  s[(size_t)b*DD + d] = acc * (1.0f/LL);
}

// ---------------- W[512][512] fp32 -> Wt[512][512] bf16 (transposed) ----------------
__global__ void transpose_bf(const float* __restrict__ in, bf16* __restrict__ out){
  __shared__ float tile[32][33];
  int tx = threadIdx.x, ty = threadIdx.y;       // 32 x 8
  int bx = blockIdx.x*32, by = blockIdx.y*32;
  #pragma unroll
  for (int j = 0; j < 32; j += 8)
    tile[ty + j][tx] = in[(size_t)(by + ty + j)*DD + bx + tx];
  __syncthreads();
  #pragma unroll
  for (int j = 0; j < 32; j += 8)
    out[(size_t)(bx + ty + j)*DD + by + tx] = __float2bfloat16(tile[tx][ty + j]);
}

// ---------------- MFMA GEMM: C[M,N] = A[M,512](bf16) @ Wt[N,512]^T(bf16) + bias ----------------
__global__ __launch_bounds__(256)
void gemm_mfma(const bf16* __restrict__ A, const bf16* __restrict__ Wt,
               const float* __restrict__ b0, const float* __restrict__ b1,
               const float* __restrict__ b2, float* __restrict__ C, int N){
  const int K = 512;
  __shared__ bf16 As[128*32];
  __shared__ bf16 Bs[128*32];
  int t = threadIdx.x;
  int wave = t >> 6, lane = t & 63;
  int bm = blockIdx.y * 128, bn = blockIdx.x * 128;
  int wm = (wave & 1) * 64, wn = (wave >> 1) * 64;
  ffrag acc[4][4];
  #pragma unroll
  for (int i = 0; i < 4; i++)
    #pragma unroll
    for (int j = 0; j < 4; j++) acc[i][j] = (ffrag){0.f,0.f,0.f,0.f};

  int srow = t >> 2;
  int scol = (t & 3) * 8;
  const bf16* gA = A  + (size_t)(bm + srow)*K + scol;
  const bf16* gB = Wt + (size_t)(bn + srow)*K + scol;
  char* lA = (char*)As + 16*t;
  char* lB = (char*)Bs + 16*t;
  int q = lane >> 4, r = lane & 15;

  for (int k0 = 0; k0 < K; k0 += 32){
    gld16(gA + k0,          lA);
    gld16(gA + 64*K + k0,   lA + 4096);
    gld16(gB + k0,          lB);
    gld16(gB + 64*K + k0,   lB + 4096);
    __syncthreads();
    bfrag af[4], bfv[4];
    #pragma unroll
    for (int i = 0; i < 4; i++){
      af[i]  = *(const bfrag*)(As + (wm + i*16 + r)*32 + q*8);
      bfv[i] = *(const bfrag*)(Bs + (wn + i*16 + r)*32 + q*8);
    }
    #pragma unroll
    for (int i = 0; i < 4; i++)
      #pragma unroll
      for (int j = 0; j < 4; j++)
        acc[i][j] = __builtin_amdgcn_mfma_f32_16x16x32_bf16(af[i], bfv[j], acc[i][j], 0, 0, 0);
    __syncthreads();
  }
  #pragma unroll
  for (int i = 0; i < 4; i++){
    #pragma unroll
    for (int j = 0; j < 4; j++){
      int row = bm + wm + i*16 + q*4;
      int col = bn + wn + j*16 + r;
      const float* bp = (col < 512) ? b0 : (col < 1024) ? b1 : b2;
      float bias = bp[col & 511];
      #pragma unroll
      for (int g = 0; g < 4; g++)
        C[(size_t)(row + g)*N + col] = acc[i][j][g] + bias;
    }
  }
}

// ---------------- batched s-projections ----------------
__global__ __launch_bounds__(256)
void s_proj(const float* __restrict__ A,
            const float* __restrict__ W0, const float* __restrict__ W1,
            const float* __restrict__ W2, const float* __restrict__ W3,
            const float* __restrict__ W4,
            const float* __restrict__ bias0, const float* __restrict__ bias1,
            const float* __restrict__ bias2, const float* __restrict__ bias3,
            const float* __restrict__ bias4,
            float* __restrict__ O0, float* __restrict__ O1,
            float* __restrict__ O2, float* __restrict__ O3,
            float* __restrict__ O4,
            int ldc0, int ldc1, int ldc2, int ldc3, int ldc4){
  __shared__ float part[4][64][17];
  int t = threadIdx.x;
  int n = t & 63, kg = t >> 6;
  int wi = blockIdx.x >> 3, ch = blockIdx.x & 7;
  const float* W  = (wi==0)?W0:(wi==1)?W1:(wi==2)?W2:(wi==3)?W3:W4;
  const float* bs = (wi==0)?bias0:(wi==1)?bias1:(wi==2)?bias2:(wi==3)?bias3:bias4;
  float* O  = (wi==0)?O0:(wi==1)?O1:(wi==2)?O2:(wi==3)?O3:O4;
  int ldc   = (wi==0)?ldc0:(wi==1)?ldc1:(wi==2)?ldc2:(wi==3)?ldc3:ldc4;
  int col = ch*64 + n;
  float acc[16];
  #pragma unroll
  for (int m = 0; m < 16; m++) acc[m] = 0.f;
  const float* Wp = W + (size_t)(kg*128)*512 + col;
  const float* Ap = A + kg*128;
  for (int k = 0; k < 128; k++){
    float w = Wp[(size_t)k*512];
    #pragma unroll
    for (int m = 0; m < 16; m++) acc[m] = fmaf(Ap[m*512 + k], w, acc[m]);
  }
  #pragma unroll
  for (int m = 0; m < 16; m++) part[kg][n][m] = acc[m];
  __syncthreads();
  for (int o = t; o < 1024; o += 256){
    int m = o >> 6, nn = o & 63;
    float v = part[0][nn][m] + part[1][nn][m] + part[2][nn][m] + part[3][nn][m];
    O[(size_t)m*ldc + ch*64 + nn] = v + bs[ch*64 + nn];
  }
}

// ---------------- sat attention ----------------
__global__ void sat_attn(const float* __restrict__ qkv, const float* __restrict__ KeVe,
                         const float* __restrict__ KsVs, bf16* __restrict__ ctx){
  int gw = blockIdx.x*(blockDim.x >> 6) + (threadIdx.x >> 6);
  int lane = threadIdx.x & 63;
  int hh = gw & (NHH-1);
  int t  = gw >> 3;
  int b = t >> 9, l = t & 511;
  int base = hh*HDD + lane;
  float qv = qkv[(size_t)t*1536 + base];
  int t0 = (b << 9) | ((l + 1) & 511);
  int t2 = (b << 9) | (l == 0 ? 511 : 0);
  float k[5];
  k[0] = qkv [(size_t)t0*1536 + 512 + base];
  k[1] = qkv [(size_t)t *1536 + 512 + base];
  k[2] = qkv [(size_t)t2*1536 + 512 + base];
  k[3] = KeVe[(size_t)t *1024 + base];
  k[4] = KsVs[(size_t)b *1024 + base];
  float sc[5];
  #pragma unroll
  for (int j = 0; j < 5; j++){
    float v = qv * k[j];
    #pragma unroll
    for (int off = 32; off; off >>= 1) v += __shfl_xor(v, off, 64);
    sc[j] = v * 0.125f;
  }
  float m = fmaxf(fmaxf(fmaxf(sc[0],sc[1]), fmaxf(sc[2],sc[3])), sc[4]);
  float p[5], den = 0.f;
  #pragma unroll
  for (int j = 0; j < 5; j++){ p[j] = __expf(sc[j]-m); den += p[j]; }
  float inv = 1.0f/den;
  float v0 = qkv [(size_t)t0*1536 + 1024 + base];
  float v1 = qkv [(size_t)t *1536 + 1024 + base];
  float v2 = qkv [(size_t)t2*1536 + 1024 + base];
  float v3 = KeVe[(size_t)t *1024 + 512 + base];
  float v4 = KsVs[(size_t)b *1024 + 512 + base];
  float o = (p[0]*v0 + p[1]*v1 + p[2]*v2 + p[3]*v3 + p[4]*v4) * inv;
  ctx[(size_t)t*DD + base] = __float2bfloat16(o);
}

// ---------------- rel attention pass 1: partial softmax per key-chunk ----------------
// grid (RCH, NHH, BB); workspace pws[b][h][ch][66] = {part[64], m_c, l_c}
__global__ __launch_bounds__(256)
void rel_part(const float* __restrict__ q, const float* __restrict__ Ksr,
              const float* __restrict__ Vsr, const float* __restrict__ KV,
              float* __restrict__ pws){
  int ch = blockIdx.x, hh = blockIdx.y, b = blockIdx.z;
  int t = threadIdx.x;
  int base = hh * HDD;
  __shared__ __align__(16) float qs[64];
  __shared__ float sc[RCK];
  __shared__ float red[256];
  __shared__ float part[4][64];
  int j0 = ch * RCK;
  int nk = min(513 - j0, RCK);
  if (t < 64) qs[t] = q[(size_t)b*DD + base + t];
  __syncthreads();
  if (t < nk){
    int j = j0 + t;
    const float* kr = (j == 0) ? (Ksr + (size_t)b*DD + base)
                               : (KV + ((size_t)b*LL + j - 1)*1024 + base);
    float a = 0.f;
    #pragma unroll
    for (int d = 0; d < 64; d += 4){
      float4 k4 = *(const float4*)(kr + d);
      float4 q4 = *(const float4*)(qs + d);
      a += q4.x*k4.x + q4.y*k4.y + q4.z*k4.z + q4.w*k4.w;
    }
    sc[t] = a * 0.125f;
  }
  __syncthreads();
  red[t] = (t < nk) ? sc[t] : -1e30f; __syncthreads();
  for (int st = 128; st; st >>= 1){ if (t < st) red[t] = fmaxf(red[t], red[t+st]); __syncthreads(); }
  float m = red[0]; __syncthreads();
  if (t < nk) sc[t] = __expf(sc[t] - m);
  __syncthreads();
  red[t] = (t < nk) ? sc[t] : 0.f; __syncthreads();
  for (int st = 128; st; st >>= 1){ if (t < st) red[t] += red[t+st]; __syncthreads(); }
  float l = red[0];
  int d = t & 63, c2 = t >> 6;
  float a = 0.f;
  for (int j = c2; j < nk; j += 4){
    int gj = j0 + j;
    float vv = (gj == 0) ? Vsr[(size_t)b*DD + base + d]
                         : KV[((size_t)b*LL + gj - 1)*1024 + 512 + base + d];
    a += sc[j] * vv;
  }
  part[c2][d] = a; __syncthreads();
  float* o = pws + (((size_t)(b*NHH + hh))*RCH + ch) * 66;
  if (t < 64) o[t] = part[0][t] + part[1][t] + part[2][t] + part[3][t];
  else if (t == 64) o[64] = m;
  else if (t == 65) o[65] = l;
}

// ---------------- rel attention pass 2: combine chunks ----------------
__global__ void rel_comb(const float* __restrict__ pws, float* __restrict__ ctx){
  int bh = blockIdx.x;    // 0..127
  int t = threadIdx.x;    // 64
  const float* p = pws + (size_t)bh*RCH*66;
  float M = -1e30f;
  #pragma unroll
  for (int c = 0; c < RCH; c++) M = fmaxf(M, p[c*66 + 64]);
  float den = 0.f, acc = 0.f;
  #pragma unroll
  for (int c = 0; c < RCH; c++){
    float w = __expf(p[c*66 + 64] - M);
    den += w * p[c*66 + 65];
    acc += w * p[c*66 + t];
  }
  int b = bh >> 3, hh = bh & 7;
  ctx[(size_t)b*DD + hh*HDD + t] = acc / den;
}

// ---------------- y = ln_w * norm(relu(x)) + ln_b (+ bf16 shadow; fp32 opt.) ----------------
__global__ void relu_ln(const float* __restrict__ X, const float* __restrict__ w,
                        const float* __restrict__ bn, float* __restrict__ Y,
                        bf16* __restrict__ Ybf, int writeY){
  int row = blockIdx.x;
  int tid = threadIdx.x; // 256
  __shared__ float red[256];
  const float* x = X + (size_t)row*DD;
  float v0 = fmaxf(x[tid], 0.f), v1 = fmaxf(x[tid+256], 0.f);
  red[tid] = v0 + v1;
  __syncthreads();
  for (int st = 128; st; st >>= 1){ if (tid < st) red[tid] += red[tid+st]; __syncthreads(); }
  float u = red[0] * (1.0f/DD);
  __syncthreads();
  float d0 = v0 - u, d1 = v1 - u;
  red[tid] = d0*d0 + d1*d1;
  __syncthreads();
  for (int st = 128; st; st >>= 1){ if (tid < st) red[tid] += red[tid+st]; __syncthreads(); }
  float var = red[0] * (1.0f/DD);
  float inv = rsqrtf(var + 1e-12f);
  float y0 = w[tid]    *d0*inv + bn[tid];
  float y1 = w[tid+256]*d1*inv + bn[tid+256];
  if (writeY){
    Y[(size_t)row*DD + tid]       = y0;
    Y[(size_t)row*DD + tid + 256] = y1;
  }
  Ybf[(size_t)row*DD + tid]       = __float2bfloat16(y0);
  Ybf[(size_t)row*DD + tid + 256] = __float2bfloat16(y1);
}

// ---------------- logits: C[8192,17] = h[8192,512] @ W[512,17] + b (fp32) ----------------
__global__ __launch_bounds__(256)
void logits_kernel(const float* __restrict__ h, const float* __restrict__ W,
                   const float* __restrict__ bias, float* __restrict__ out){
  int t = threadIdx.x;
  if (t >= 255) return;
  int m = blockIdx.x*15 + t/17;
  int n = t % 17;
  if (m >= MM) return;
  const float* hr = h + (size_t)m*DD;
  float acc = 0.f;
  for (int k = 0; k < 512; k += 4){
    float4 h4 = *(const float4*)(hr + k);
    acc += h4.x*W[(size_t)(k+0)*TT + n] + h4.y*W[(size_t)(k+1)*TT + n]
         + h4.z*W[(size_t)(k+2)*TT + n] + h4.w*W[(size_t)(k+3)*TT + n];
  }
  out[(size_t)m*TT + n] = acc + bias[n];
}

extern "C" void kernel_launch(void* const* d_in, const int* in_sizes, int n_in,
                              void* d_out, int out_size, void* d_ws, size_t ws_size,
                              hipStream_t stream) {
  const int*   tokens  = (const int*)  d_in[0];
  const float* emb     = (const float*)d_in[4];
  const float* sat_qw  = (const float*)d_in[5];
  const float* sat_qb  = (const float*)d_in[6];
  const float* sat_kw  = (const float*)d_in[7];
  const float* sat_kb  = (const float*)d_in[8];
  const float* sat_vw  = (const float*)d_in[9];
  const float* sat_vb  = (const float*)d_in[10];
  const float* sat_ow  = (const float*)d_in[11];
  const float* sat_ob  = (const float*)d_in[12];
  const float* rel_qw  = (const float*)d_in[13];
  const float* rel_qb  = (const float*)d_in[14];
  const float* rel_kw  = (const float*)d_in[15];
  const float* rel_kb  = (const float*)d_in[16];
  const float* rel_vw  = (const float*)d_in[17];
  const float* rel_vb  = (const float*)d_in[18];
  const float* rel_ow  = (const float*)d_in[19];
  const float* rel_ob  = (const float*)d_in[20];
  const float* ln_sat_w= (const float*)d_in[21];
  const float* ln_sat_b= (const float*)d_in[22];
  const float* ln_rel_w= (const float*)d_in[23];
  const float* ln_rel_b= (const float*)d_in[24];
  const float* ofc_w   = (const float*)d_in[25];
  const float* ofc_b   = (const float*)d_in[26];

  char* p = (char*)d_ws;
  auto alloc = [&](size_t bytes) -> char* {
    char* r = p; p += (bytes + 255) & ~(size_t)255; return r;
  };
  const size_t BIGB = (size_t)MM*DD*4;         // 16 MB
  float* e     = (float*)alloc(BIGB);
  float* h     = (float*)alloc(BIGB);
  bf16*  ebf   = (bf16*) alloc(BIGB/2);
  float* KeVe  = (float*)alloc(2*BIGB);
  float* qkv   = (float*)alloc(3*BIGB);
  bf16*  ctxbf = (bf16*) alloc(BIGB/2);
  bf16*  WtSat = (bf16*) alloc((size_t)1536*512*2);
  bf16*  WtRel = (bf16*) alloc((size_t)1024*512*2);
  bf16*  WtO   = (bf16*) alloc((size_t)512*512*2);
  float* s     = (float*)alloc(BB*DD*4);
  float* KsVs  = (float*)alloc(BB*1024*4);
  float* qr    = (float*)alloc(BB*DD*4);
  float* Ksr   = (float*)alloc(BB*DD*4);
  float* Vsr   = (float*)alloc(BB*DD*4);
  float* cr    = (float*)alloc(BB*DD*4);
  float* rr    = (float*)alloc(BB*DD*4);
  bf16*  sbfd  = (bf16*) alloc(BB*DD*2);
  float* pws   = (float*)alloc((size_t)BB*NHH*RCH*66*4);   // rel partials
  bf16*  hbf   = ebf;
  float* aout  = qkv;
  float* kv    = qkv + (size_t)MM*512;

  dim3 tb(32, 8);
  dim3 tg(16, 16);
  int total = MM*DD;

  embed_kernel<<<(total+255)/256, 256, 0, stream>>>(tokens, emb, e, ebf, total);
  mean_kernel<<<(BB*DD)/256, 256, 0, stream>>>(e, s);

  transpose_bf<<<tg, tb, 0, stream>>>(sat_qw, WtSat);
  transpose_bf<<<tg, tb, 0, stream>>>(sat_kw, WtSat + (size_t)512*512);
  transpose_bf<<<tg, tb, 0, stream>>>(sat_vw, WtSat + (size_t)1024*512);
  transpose_bf<<<tg, tb, 0, stream>>>(rel_kw, WtRel);
  transpose_bf<<<tg, tb, 0, stream>>>(rel_vw, WtRel + (size_t)512*512);
  transpose_bf<<<tg, tb, 0, stream>>>(sat_ow, WtO);

  gemm_mfma<<<dim3(8,64), 256, 0, stream>>>(ebf, WtSat + (size_t)512*512,
                                            sat_kb, sat_vb, sat_vb, KeVe, 1024);

  for (int c = 0; c < 2; c++){
    const bf16* hc = (c == 0) ? ebf : hbf;
    gemm_mfma<<<dim3(12,64), 256, 0, stream>>>(hc, WtSat, sat_qb, sat_kb, sat_vb, qkv, 1536);
    s_proj<<<40, 256, 0, stream>>>(s,
        sat_kw, sat_vw, rel_qw, rel_kw, rel_vw,
        sat_kb, sat_vb, rel_qb, rel_kb, rel_vb,
        KsVs, KsVs + 512, qr, Ksr, Vsr,
        1024, 1024, 512, 512, 512);
    sat_attn<<<MM*NHH/4, 256, 0, stream>>>(qkv, KeVe, KsVs, ctxbf);
    gemm_mfma<<<dim3(4,64), 256, 0, stream>>>(ctxbf, WtO, sat_ob, sat_ob, sat_ob, aout, 512);
    relu_ln<<<MM, 256, 0, stream>>>(aout, ln_sat_w, ln_sat_b, h, hbf, (c == 1));
    gemm_mfma<<<dim3(8,64), 256, 0, stream>>>(hbf, WtRel, rel_kb, rel_vb, rel_vb, kv, 1024);
    rel_part<<<dim3(RCH, NHH, BB), 256, 0, stream>>>(qr, Ksr, Vsr, kv, pws);
    rel_comb<<<BB*NHH, 64, 0, stream>>>(pws, cr);
    s_proj<<<8, 256, 0, stream>>>(cr,
        rel_ow, rel_ow, rel_ow, rel_ow, rel_ow,
        rel_ob, rel_ob, rel_ob, rel_ob, rel_ob,
        rr, rr, rr, rr, rr,
        512, 512, 512, 512, 512);
    // NOTE: s MUST be written here (writeY=1) — it feeds the next cycle.
    // Round-5 bug: writeY=0 left s as workspace poison -> absmax 0.98.
    relu_ln<<<BB, 256, 0, stream>>>(rr, ln_rel_w, ln_rel_b, s, sbfd, 1);
  }

  logits_kernel<<<(MM + 14)/15, 256, 0, stream>>>(h, ofc_w, ofc_b, (float*)d_out);
}

// Round 7
// 481.194 us; speedup vs baseline: 6.0644x; 1.2001x over previous
//
#include <hip/hip_runtime.h>
#include <hip/hip_bf16.h>

typedef __hip_bfloat16 bf16;

#define BB 16
#define LL 512
#define DD 512
#define NHH 8
#define HDD 64
#define TT 17
#define MM (BB*LL)   // 8192 rows
#define RCH 8        // rel-attn key chunks
#define RCK 65       // keys per chunk (8*65=520 >= 513)

typedef __attribute__((ext_vector_type(8))) short bfrag;   // 8 bf16
typedef __attribute__((ext_vector_type(4))) float ffrag;   // 4 fp32

static __device__ __forceinline__ void gld16(const void* g, void* l){
  __builtin_amdgcn_global_load_lds((const __attribute__((address_space(1))) void*)g,
                                   (__attribute__((address_space(3))) void*)l, 16, 0, 0);
}

// ---------------- embedding gather (fp32 + bf16 shadow) ----------------
__global__ void embed_kernel(const int* __restrict__ tokens, const float* __restrict__ emb,
                             float* __restrict__ e, bf16* __restrict__ ebf, int total){
  int i = blockIdx.x*blockDim.x + threadIdx.x;
  if (i < total) {
    int t = tokens[i >> 9];
    int d = i & 511;
    float v = emb[(size_t)t*DD + d];
    e[i] = v;
    ebf[i] = __float2bfloat16(v);
  }
}

// ---------------- s[b,d] = mean_l e[b,l,d] ----------------
__global__ void mean_kernel(const float* __restrict__ e, float* __restrict__ s){
  int i = blockIdx.x*blockDim.x + threadIdx.x;
  int b = i >> 9, d = i & 511;
  const float* p = e + (size_t)b*LL*DD + d;
  float acc = 0.f;
  for (int l = 0; l < LL; l++) acc += p[(size_t)l*DD];
  s[(size_t)b*DD + d] = acc * (1.0f/LL);
}

// ---------------- W[512][512] fp32 -> Wt[512][512] bf16 (transposed) ----------------
__global__ void transpose_bf(const float* __restrict__ in, bf16* __restrict__ out){
  __shared__ float tile[32][33];
  int tx = threadIdx.x, ty = threadIdx.y;       // 32 x 8
  int bx = blockIdx.x*32, by = blockIdx.y*32;
  #pragma unroll
  for (int j = 0; j < 32; j += 8)
    tile[ty + j][tx] = in[(size_t)(by + ty + j)*DD + bx + tx];
  __syncthreads();
  #pragma unroll
  for (int j = 0; j < 32; j += 8)
    out[(size_t)(bx + ty + j)*DD + by + tx] = __float2bfloat16(tile[tx][ty + j]);
}

// ---------------- ofc_w[512][17] -> WtLog[128][512] bf16 (transposed, zero-padded) ----------------
__global__ void pad_logw(const float* __restrict__ w, bf16* __restrict__ out){
  int i = blockIdx.x*blockDim.x + threadIdx.x;   // 128*512 total
  int row = i >> 9, k = i & 511;
  out[i] = __float2bfloat16(row < TT ? w[(size_t)k*TT + row] : 0.f);
}

// ---------------- MFMA GEMM: C[M,N] = A[M,512](bf16) @ Wt[N,512]^T(bf16) + bias ----------------
__global__ __launch_bounds__(256)
void gemm_mfma(const bf16* __restrict__ A, const bf16* __restrict__ Wt,
               const float* __restrict__ b0, const float* __restrict__ b1,
               const float* __restrict__ b2, float* __restrict__ C, int N){
  const int K = 512;
  __shared__ bf16 As[128*32];
  __shared__ bf16 Bs[128*32];
  int t = threadIdx.x;
  int wave = t >> 6, lane = t & 63;
  int bm = blockIdx.y * 128, bn = blockIdx.x * 128;
  int wm = (wave & 1) * 64, wn = (wave >> 1) * 64;
  ffrag acc[4][4];
  #pragma unroll
  for (int i = 0; i < 4; i++)
    #pragma unroll
    for (int j = 0; j < 4; j++) acc[i][j] = (ffrag){0.f,0.f,0.f,0.f};

  int srow = t >> 2;
  int scol = (t & 3) * 8;
  const bf16* gA = A  + (size_t)(bm + srow)*K + scol;
  const bf16* gB = Wt + (size_t)(bn + srow)*K + scol;
  char* lA = (char*)As + 16*t;
  char* lB = (char*)Bs + 16*t;
  int q = lane >> 4, r = lane & 15;

  for (int k0 = 0; k0 < K; k0 += 32){
    gld16(gA + k0,          lA);
    gld16(gA + 64*K + k0,   lA + 4096);
    gld16(gB + k0,          lB);
    gld16(gB + 64*K + k0,   lB + 4096);
    __syncthreads();
    bfrag af[4], bfv[4];
    #pragma unroll
    for (int i = 0; i < 4; i++){
      af[i]  = *(const bfrag*)(As + (wm + i*16 + r)*32 + q*8);
      bfv[i] = *(const bfrag*)(Bs + (wn + i*16 + r)*32 + q*8);
    }
    #pragma unroll
    for (int i = 0; i < 4; i++)
      #pragma unroll
      for (int j = 0; j < 4; j++)
        acc[i][j] = __builtin_amdgcn_mfma_f32_16x16x32_bf16(af[i], bfv[j], acc[i][j], 0, 0, 0);
    __syncthreads();
  }
  #pragma unroll
  for (int i = 0; i < 4; i++){
    #pragma unroll
    for (int j = 0; j < 4; j++){
      int row = bm + wm + i*16 + q*4;
      int col = bn + wn + j*16 + r;
      const float* bp = (col < 512) ? b0 : (col < 1024) ? b1 : b2;
      float bias = bp[col & 511];
      #pragma unroll
      for (int g = 0; g < 4; g++)
        C[(size_t)(row + g)*N + col] = acc[i][j][g] + bias;
    }
  }
}

// ---------------- logits MFMA: d_out[8192,17] = hbf @ WtLog^T + ofc_b ----------------
__global__ __launch_bounds__(256)
void gemm_logits(const bf16* __restrict__ A, const bf16* __restrict__ Wt,
                 const float* __restrict__ bias, float* __restrict__ C){
  const int K = 512;
  __shared__ bf16 As[128*32];
  __shared__ bf16 Bs[128*32];
  int t = threadIdx.x;
  int wave = t >> 6, lane = t & 63;
  int bm = blockIdx.y * 128;
  int wm = (wave & 1) * 64, wn = (wave >> 1) * 64;
  ffrag acc[4][4];
  #pragma unroll
  for (int i = 0; i < 4; i++)
    #pragma unroll
    for (int j = 0; j < 4; j++) acc[i][j] = (ffrag){0.f,0.f,0.f,0.f};

  int srow = t >> 2;
  int scol = (t & 3) * 8;
  const bf16* gA = A  + (size_t)(bm + srow)*K + scol;
  const bf16* gB = Wt + (size_t)srow*K + scol;
  char* lA = (char*)As + 16*t;
  char* lB = (char*)Bs + 16*t;
  int q = lane >> 4, r = lane & 15;

  for (int k0 = 0; k0 < K; k0 += 32){
    gld16(gA + k0,          lA);
    gld16(gA + 64*K + k0,   lA + 4096);
    gld16(gB + k0,          lB);
    gld16(gB + 64*K + k0,   lB + 4096);
    __syncthreads();
    bfrag af[4], bfv[4];
    #pragma unroll
    for (int i = 0; i < 4; i++){
      af[i]  = *(const bfrag*)(As + (wm + i*16 + r)*32 + q*8);
      bfv[i] = *(const bfrag*)(Bs + (wn + i*16 + r)*32 + q*8);
    }
    #pragma unroll
    for (int i = 0; i < 4; i++)
      #pragma unroll
      for (int j = 0; j < 4; j++)
        acc[i][j] = __builtin_amdgcn_mfma_f32_16x16x32_bf16(af[i], bfv[j], acc[i][j], 0, 0, 0);
    __syncthreads();
  }
  #pragma unroll
  for (int i = 0; i < 4; i++){
    #pragma unroll
    for (int j = 0; j < 4; j++){
      int row = bm + wm + i*16 + q*4;
      int col = wn + j*16 + r;
      if (col < TT){
        float bias_v = bias[col];
        #pragma unroll
        for (int g = 0; g < 4; g++)
          C[(size_t)(row + g)*TT + col] = acc[i][j][g] + bias_v;
      }
    }
  }
}

// ---------------- batched s-projections: 8-way split-k, 32-col chunks ----------------
__global__ __launch_bounds__(256)
void s_proj(const float* __restrict__ A,
            const float* __restrict__ W0, const float* __restrict__ W1,
            const float* __restrict__ W2, const float* __restrict__ W3,
            const float* __restrict__ W4,
            const float* __restrict__ bias0, const float* __restrict__ bias1,
            const float* __restrict__ bias2, const float* __restrict__ bias3,
            const float* __restrict__ bias4,
            float* __restrict__ O0, float* __restrict__ O1,
            float* __restrict__ O2, float* __restrict__ O3,
            float* __restrict__ O4,
            int ldc0, int ldc1, int ldc2, int ldc3, int ldc4){
  __shared__ float part[8][32][17];
  int t = threadIdx.x;
  int n = t & 31, kg = t >> 5;            // 32 cols x 8 k-groups (64 k each)
  int wi = blockIdx.x >> 4, ch = blockIdx.x & 15;
  const float* W  = (wi==0)?W0:(wi==1)?W1:(wi==2)?W2:(wi==3)?W3:W4;
  const float* bs = (wi==0)?bias0:(wi==1)?bias1:(wi==2)?bias2:(wi==3)?bias3:bias4;
  float* O  = (wi==0)?O0:(wi==1)?O1:(wi==2)?O2:(wi==3)?O3:O4;
  int ldc   = (wi==0)?ldc0:(wi==1)?ldc1:(wi==2)?ldc2:(wi==3)?ldc3:ldc4;
  int col = ch*32 + n;
  float acc[16];
  #pragma unroll
  for (int m = 0; m < 16; m++) acc[m] = 0.f;
  const float* Wp = W + (size_t)(kg*64)*512 + col;
  const float* Ap = A + kg*64;            // wave-uniform -> scalar loads
  for (int k = 0; k < 64; k++){
    float w = Wp[(size_t)k*512];
    #pragma unroll
    for (int m = 0; m < 16; m++) acc[m] = fmaf(Ap[m*512 + k], w, acc[m]);
  }
  #pragma unroll
  for (int m = 0; m < 16; m++) part[kg][n][m] = acc[m];
  __syncthreads();
  for (int o = t; o < 512; o += 256){
    int m = o >> 5, nn = o & 31;
    float v = 0.f;
    #pragma unroll
    for (int g = 0; g < 8; g++) v += part[g][nn][m];
    O[(size_t)m*ldc + ch*32 + nn] = v + bs[ch*32 + nn];
  }
}

// ---------------- sat attention ----------------
__global__ void sat_attn(const float* __restrict__ qkv, const float* __restrict__ KeVe,
                         const float* __restrict__ KsVs, bf16* __restrict__ ctx){
  int gw = blockIdx.x*(blockDim.x >> 6) + (threadIdx.x >> 6);
  int lane = threadIdx.x & 63;
  int hh = gw & (NHH-1);
  int t  = gw >> 3;
  int b = t >> 9, l = t & 511;
  int base = hh*HDD + lane;
  float qv = qkv[(size_t)t*1536 + base];
  int t0 = (b << 9) | ((l + 1) & 511);
  int t2 = (b << 9) | (l == 0 ? 511 : 0);
  float k[5];
  k[0] = qkv [(size_t)t0*1536 + 512 + base];
  k[1] = qkv [(size_t)t *1536 + 512 + base];
  k[2] = qkv [(size_t)t2*1536 + 512 + base];
  k[3] = KeVe[(size_t)t *1024 + base];
  k[4] = KsVs[(size_t)b *1024 + base];
  float sc[5];
  #pragma unroll
  for (int j = 0; j < 5; j++){
    float v = qv * k[j];
    #pragma unroll
    for (int off = 32; off; off >>= 1) v += __shfl_xor(v, off, 64);
    sc[j] = v * 0.125f;
  }
  float m = fmaxf(fmaxf(fmaxf(sc[0],sc[1]), fmaxf(sc[2],sc[3])), sc[4]);
  float p[5], den = 0.f;
  #pragma unroll
  for (int j = 0; j < 5; j++){ p[j] = __expf(sc[j]-m); den += p[j]; }
  float inv = 1.0f/den;
  float v0 = qkv [(size_t)t0*1536 + 1024 + base];
  float v1 = qkv [(size_t)t *1536 + 1024 + base];
  float v2 = qkv [(size_t)t2*1536 + 1024 + base];
  float v3 = KeVe[(size_t)t *1024 + 512 + base];
  float v4 = KsVs[(size_t)b *1024 + 512 + base];
  float o = (p[0]*v0 + p[1]*v1 + p[2]*v2 + p[3]*v3 + p[4]*v4) * inv;
  ctx[(size_t)t*DD + base] = __float2bfloat16(o);
}

// ---------------- rel attention pass 1: partial softmax per key-chunk ----------------
__global__ __launch_bounds__(256)
void rel_part(const float* __restrict__ q, const float* __restrict__ Ksr,
              const float* __restrict__ Vsr, const float* __restrict__ KV,
              float* __restrict__ pws){
  int ch = blockIdx.x, hh = blockIdx.y, b = blockIdx.z;
  int t = threadIdx.x;
  int base = hh * HDD;
  __shared__ __align__(16) float qs[64];
  __shared__ float sc[RCK];
  __shared__ float red[256];
  __shared__ float part[4][64];
  int j0 = ch * RCK;
  int nk = min(513 - j0, RCK);
  if (t < 64) qs[t] = q[(size_t)b*DD + base + t];
  __syncthreads();
  if (t < nk){
    int j = j0 + t;
    const float* kr = (j == 0) ? (Ksr + (size_t)b*DD + base)
                               : (KV + ((size_t)b*LL + j - 1)*1024 + base);
    float a = 0.f;
    #pragma unroll
    for (int d = 0; d < 64; d += 4){
      float4 k4 = *(const float4*)(kr + d);
      float4 q4 = *(const float4*)(qs + d);
      a += q4.x*k4.x + q4.y*k4.y + q4.z*k4.z + q4.w*k4.w;
    }
    sc[t] = a * 0.125f;
  }
  __syncthreads();
  red[t] = (t < nk) ? sc[t] : -1e30f; __syncthreads();
  for (int st = 128; st; st >>= 1){ if (t < st) red[t] = fmaxf(red[t], red[t+st]); __syncthreads(); }
  float m = red[0]; __syncthreads();
  if (t < nk) sc[t] = __expf(sc[t] - m);
  __syncthreads();
  red[t] = (t < nk) ? sc[t] : 0.f; __syncthreads();
  for (int st = 128; st; st >>= 1){ if (t < st) red[t] += red[t+st]; __syncthreads(); }
  float l = red[0];
  int d = t & 63, c2 = t >> 6;
  float a = 0.f;
  for (int j = c2; j < nk; j += 4){
    int gj = j0 + j;
    float vv = (gj == 0) ? Vsr[(size_t)b*DD + base + d]
                         : KV[((size_t)b*LL + gj - 1)*1024 + 512 + base + d];
    a += sc[j] * vv;
  }
  part[c2][d] = a; __syncthreads();
  float* o = pws + (((size_t)(b*NHH + hh))*RCH + ch) * 66;
  if (t < 64) o[t] = part[0][t] + part[1][t] + part[2][t] + part[3][t];
  else if (t == 64) o[64] = m;
  else if (t == 65) o[65] = l;
}

// ---------------- rel attention pass 2: combine chunks ----------------
__global__ void rel_comb(const float* __restrict__ pws, float* __restrict__ ctx){
  int bh = blockIdx.x;    // 0..127
  int t = threadIdx.x;    // 64
  const float* p = pws + (size_t)bh*RCH*66;
  float M = -1e30f;
  #pragma unroll
  for (int c = 0; c < RCH; c++) M = fmaxf(M, p[c*66 + 64]);
  float den = 0.f, acc = 0.f;
  #pragma unroll
  for (int c = 0; c < RCH; c++){
    float w = __expf(p[c*66 + 64] - M);
    den += w * p[c*66 + 65];
    acc += w * p[c*66 + t];
  }
  int b = bh >> 3, hh = bh & 7;
  ctx[(size_t)b*DD + hh*HDD + t] = acc / den;
}

// ---------------- y = ln_w * norm(relu(x)) + ln_b (+ bf16 shadow; fp32 opt.) ----------------
__global__ void relu_ln(const float* __restrict__ X, const float* __restrict__ w,
                        const float* __restrict__ bn, float* __restrict__ Y,
                        bf16* __restrict__ Ybf, int writeY){
  int row = blockIdx.x;
  int tid = threadIdx.x; // 256
  __shared__ float red[256];
  const float* x = X + (size_t)row*DD;
  float v0 = fmaxf(x[tid], 0.f), v1 = fmaxf(x[tid+256], 0.f);
  red[tid] = v0 + v1;
  __syncthreads();
  for (int st = 128; st; st >>= 1){ if (tid < st) red[tid] += red[tid+st]; __syncthreads(); }
  float u = red[0] * (1.0f/DD);
  __syncthreads();
  float d0 = v0 - u, d1 = v1 - u;
  red[tid] = d0*d0 + d1*d1;
  __syncthreads();
  for (int st = 128; st; st >>= 1){ if (tid < st) red[tid] += red[tid+st]; __syncthreads(); }
  float var = red[0] * (1.0f/DD);
  float inv = rsqrtf(var + 1e-12f);
  float y0 = w[tid]    *d0*inv + bn[tid];
  float y1 = w[tid+256]*d1*inv + bn[tid+256];
  if (writeY){
    Y[(size_t)row*DD + tid]       = y0;
    Y[(size_t)row*DD + tid + 256] = y1;
  }
  Ybf[(size_t)row*DD + tid]       = __float2bfloat16(y0);
  Ybf[(size_t)row*DD + tid + 256] = __float2bfloat16(y1);
}

extern "C" void kernel_launch(void* const* d_in, const int* in_sizes, int n_in,
                              void* d_out, int out_size, void* d_ws, size_t ws_size,
                              hipStream_t stream) {
  const int*   tokens  = (const int*)  d_in[0];
  const float* emb     = (const float*)d_in[4];
  const float* sat_qw  = (const float*)d_in[5];
  const float* sat_qb  = (const float*)d_in[6];
  const float* sat_kw  = (const float*)d_in[7];
  const float* sat_kb  = (const float*)d_in[8];
  const float* sat_vw  = (const float*)d_in[9];
  const float* sat_vb  = (const float*)d_in[10];
  const float* sat_ow  = (const float*)d_in[11];
  const float* sat_ob  = (const float*)d_in[12];
  const float* rel_qw  = (const float*)d_in[13];
  const float* rel_qb  = (const float*)d_in[14];
  const float* rel_kw  = (const float*)d_in[15];
  const float* rel_kb  = (const float*)d_in[16];
  const float* rel_vw  = (const float*)d_in[17];
  const float* rel_vb  = (const float*)d_in[18];
  const float* rel_ow  = (const float*)d_in[19];
  const float* rel_ob  = (const float*)d_in[20];
  const float* ln_sat_w= (const float*)d_in[21];
  const float* ln_sat_b= (const float*)d_in[22];
  const float* ln_rel_w= (const float*)d_in[23];
  const float* ln_rel_b= (const float*)d_in[24];
  const float* ofc_w   = (const float*)d_in[25];
  const float* ofc_b   = (const float*)d_in[26];

  char* p = (char*)d_ws;
  auto alloc = [&](size_t bytes) -> char* {
    char* r = p; p += (bytes + 255) & ~(size_t)255; return r;
  };
  const size_t BIGB = (size_t)MM*DD*4;         // 16 MB
  float* e     = (float*)alloc(BIGB);
  bf16*  ebf   = (bf16*) alloc(BIGB/2);
  float* KeVe  = (float*)alloc(2*BIGB);
  float* qkv   = (float*)alloc(3*BIGB);
  bf16*  ctxbf = (bf16*) alloc(BIGB/2);
  bf16*  WtSat = (bf16*) alloc((size_t)1536*512*2);
  bf16*  WtRel = (bf16*) alloc((size_t)1024*512*2);
  bf16*  WtO   = (bf16*) alloc((size_t)512*512*2);
  bf16*  WtLog = (bf16*) alloc((size_t)128*512*2);
  float* s     = (float*)alloc(BB*DD*4);
  float* KsVs  = (float*)alloc(BB*1024*4);
  float* qr    = (float*)alloc(BB*DD*4);
  float* Ksr   = (float*)alloc(BB*DD*4);
  float* Vsr   = (float*)alloc(BB*DD*4);
  float* cr    = (float*)alloc(BB*DD*4);
  float* rr    = (float*)alloc(BB*DD*4);
  bf16*  sbfd  = (bf16*) alloc(BB*DD*2);
  float* pws   = (float*)alloc((size_t)BB*NHH*RCH*66*4);   // rel partials
  bf16*  hbf   = ebf;                           // reuse: e_bf dead after cycle-0 QKV
  float* aout  = qkv;
  float* kv    = qkv + (size_t)MM*512;
  float* hdummy= (float*)e;                     // never written (writeY=0)

  dim3 tb(32, 8);
  dim3 tg(16, 16);
  int total = MM*DD;

  embed_kernel<<<(total+255)/256, 256, 0, stream>>>(tokens, emb, e, ebf, total);
  mean_kernel<<<(BB*DD)/256, 256, 0, stream>>>(e, s);

  transpose_bf<<<tg, tb, 0, stream>>>(sat_qw, WtSat);
  transpose_bf<<<tg, tb, 0, stream>>>(sat_kw, WtSat + (size_t)512*512);
  transpose_bf<<<tg, tb, 0, stream>>>(sat_vw, WtSat + (size_t)1024*512);
  transpose_bf<<<tg, tb, 0, stream>>>(rel_kw, WtRel);
  transpose_bf<<<tg, tb, 0, stream>>>(rel_vw, WtRel + (size_t)512*512);
  transpose_bf<<<tg, tb, 0, stream>>>(sat_ow, WtO);
  pad_logw<<<256, 256, 0, stream>>>(ofc_w, WtLog);

  gemm_mfma<<<dim3(8,64), 256, 0, stream>>>(ebf, WtSat + (size_t)512*512,
                                            sat_kb, sat_vb, sat_vb, KeVe, 1024);

  for (int c = 0; c < 2; c++){
    const bf16* hc = (c == 0) ? ebf : hbf;
    gemm_mfma<<<dim3(12,64), 256, 0, stream>>>(hc, WtSat, sat_qb, sat_kb, sat_vb, qkv, 1536);
    s_proj<<<80, 256, 0, stream>>>(s,
        sat_kw, sat_vw, rel_qw, rel_kw, rel_vw,
        sat_kb, sat_vb, rel_qb, rel_kb, rel_vb,
        KsVs, KsVs + 512, qr, Ksr, Vsr,
        1024, 1024, 512, 512, 512);
    sat_attn<<<MM*NHH/4, 256, 0, stream>>>(qkv, KeVe, KsVs, ctxbf);
    gemm_mfma<<<dim3(4,64), 256, 0, stream>>>(ctxbf, WtO, sat_ob, sat_ob, sat_ob, aout, 512);
    // h kept only in bf16 (hbf); fp32 h never materialized (logits use hbf)
    relu_ln<<<MM, 256, 0, stream>>>(aout, ln_sat_w, ln_sat_b, hdummy, hbf, 0);
    gemm_mfma<<<dim3(8,64), 256, 0, stream>>>(hbf, WtRel, rel_kb, rel_vb, rel_vb, kv, 1024);
    rel_part<<<dim3(RCH, NHH, BB), 256, 0, stream>>>(qr, Ksr, Vsr, kv, pws);
    rel_comb<<<BB*NHH, 64, 0, stream>>>(pws, cr);
    s_proj<<<16, 256, 0, stream>>>(cr,
        rel_ow, rel_ow, rel_ow, rel_ow, rel_ow,
        rel_ob, rel_ob, rel_ob, rel_ob, rel_ob,
        rr, rr, rr, rr, rr,
        512, 512, 512, 512, 512);
    // s MUST be written (writeY=1) — it feeds the next cycle (round-5 bug).
    relu_ln<<<BB, 256, 0, stream>>>(rr, ln_rel_w, ln_rel_b, s, sbfd, 1);
  }

  gemm_logits<<<dim3(1,64), 256, 0, stream>>>(hbf, WtLog, ofc_b, (float*)d_out);
}

// Round 8
// 450.085 us; speedup vs baseline: 6.4835x; 1.0691x over previous
//
#include <hip/hip_runtime.h>
#include <hip/hip_bf16.h>

typedef __hip_bfloat16 bf16;

#define BB 16
#define LL 512
#define DD 512
#define NHH 8
#define HDD 64
#define TT 17
#define MM (BB*LL)   // 8192 rows
#define RCH 8        // rel-attn key chunks
#define RCK 65       // keys per chunk (8*65=520 >= 513)

typedef __attribute__((ext_vector_type(8))) short bfrag;   // 8 bf16
typedef __attribute__((ext_vector_type(4))) float ffrag;   // 4 fp32
typedef __attribute__((ext_vector_type(8))) unsigned short us8;

static __device__ __forceinline__ void gld16(const void* g, void* l){
  __builtin_amdgcn_global_load_lds((const __attribute__((address_space(1))) void*)g,
                                   (__attribute__((address_space(3))) void*)l, 16, 0, 0);
}
static __device__ __forceinline__ float us2f(unsigned short u){
  unsigned int v = ((unsigned int)u) << 16;
  float f; __builtin_memcpy(&f, &v, 4); return f;
}

// ---------------- embedding gather -> bf16 only ----------------
__global__ void embed_kernel(const int* __restrict__ tokens, const float* __restrict__ emb,
                             bf16* __restrict__ ebf, int total){
  int i = blockIdx.x*blockDim.x + threadIdx.x;
  if (i < total) {
    int t = tokens[i >> 9];
    int d = i & 511;
    ebf[i] = __float2bfloat16(emb[(size_t)t*DD + d]);
  }
}

// ---------------- s[b,d] = mean_l e[b,l,d] (bf16 in, fp32 out) ----------------
__global__ void mean_kernel(const bf16* __restrict__ e, float* __restrict__ s){
  int i = blockIdx.x*blockDim.x + threadIdx.x;
  int b = i >> 9, d = i & 511;
  const bf16* p = e + (size_t)b*LL*DD + d;
  float acc = 0.f;
  for (int l = 0; l < LL; l++) acc += __bfloat162float(p[(size_t)l*DD]);
  s[(size_t)b*DD + d] = acc * (1.0f/LL);
}

// ---------------- 6x W[512][512] fp32 -> Wt bf16 (transposed), one launch ----------------
__global__ void prep_w(const float* __restrict__ i0, const float* __restrict__ i1,
                       const float* __restrict__ i2, const float* __restrict__ i3,
                       const float* __restrict__ i4, const float* __restrict__ i5,
                       bf16* __restrict__ o0, bf16* __restrict__ o1,
                       bf16* __restrict__ o2, bf16* __restrict__ o3,
                       bf16* __restrict__ o4, bf16* __restrict__ o5){
  __shared__ float tile[32][33];
  int z = blockIdx.z;
  const float* in = (z==0)?i0:(z==1)?i1:(z==2)?i2:(z==3)?i3:(z==4)?i4:i5;
  bf16* out       = (z==0)?o0:(z==1)?o1:(z==2)?o2:(z==3)?o3:(z==4)?o4:o5;
  int tx = threadIdx.x, ty = threadIdx.y;       // 32 x 8
  int bx = blockIdx.x*32, by = blockIdx.y*32;
  #pragma unroll
  for (int j = 0; j < 32; j += 8)
    tile[ty + j][tx] = in[(size_t)(by + ty + j)*DD + bx + tx];
  __syncthreads();
  #pragma unroll
  for (int j = 0; j < 32; j += 8)
    out[(size_t)(bx + ty + j)*DD + by + tx] = __float2bfloat16(tile[tx][ty + j]);
}

// ---------------- ofc_w[512][17] -> WtLog[128][512] bf16 (transposed, zero-padded) ----------------
__global__ void pad_logw(const float* __restrict__ w, bf16* __restrict__ out){
  int i = blockIdx.x*blockDim.x + threadIdx.x;   // 128*512 total
  int row = i >> 9, k = i & 511;
  out[i] = __float2bfloat16(row < TT ? w[(size_t)k*TT + row] : 0.f);
}

// ---------------- MFMA GEMM, bf16 output: C[M,N] = A @ Wt^T + bias ----------------
__global__ __launch_bounds__(256)
void gemm_mfma_bf(const bf16* __restrict__ A, const bf16* __restrict__ Wt,
                  const float* __restrict__ b0, const float* __restrict__ b1,
                  const float* __restrict__ b2, bf16* __restrict__ C, int N){
  const int K = 512;
  __shared__ bf16 As[128*32];
  __shared__ bf16 Bs[128*32];
  int t = threadIdx.x;
  int wave = t >> 6, lane = t & 63;
  int bm = blockIdx.y * 128, bn = blockIdx.x * 128;
  int wm = (wave & 1) * 64, wn = (wave >> 1) * 64;
  ffrag acc[4][4];
  #pragma unroll
  for (int i = 0; i < 4; i++)
    #pragma unroll
    for (int j = 0; j < 4; j++) acc[i][j] = (ffrag){0.f,0.f,0.f,0.f};

  int srow = t >> 2;
  int scol = (t & 3) * 8;
  const bf16* gA = A  + (size_t)(bm + srow)*K + scol;
  const bf16* gB = Wt + (size_t)(bn + srow)*K + scol;
  char* lA = (char*)As + 16*t;
  char* lB = (char*)Bs + 16*t;
  int q = lane >> 4, r = lane & 15;

  for (int k0 = 0; k0 < K; k0 += 32){
    gld16(gA + k0,          lA);
    gld16(gA + 64*K + k0,   lA + 4096);
    gld16(gB + k0,          lB);
    gld16(gB + 64*K + k0,   lB + 4096);
    __syncthreads();
    bfrag af[4], bfv[4];
    #pragma unroll
    for (int i = 0; i < 4; i++){
      af[i]  = *(const bfrag*)(As + (wm + i*16 + r)*32 + q*8);
      bfv[i] = *(const bfrag*)(Bs + (wn + i*16 + r)*32 + q*8);
    }
    #pragma unroll
    for (int i = 0; i < 4; i++)
      #pragma unroll
      for (int j = 0; j < 4; j++)
        acc[i][j] = __builtin_amdgcn_mfma_f32_16x16x32_bf16(af[i], bfv[j], acc[i][j], 0, 0, 0);
    __syncthreads();
  }
  #pragma unroll
  for (int i = 0; i < 4; i++){
    #pragma unroll
    for (int j = 0; j < 4; j++){
      int row = bm + wm + i*16 + q*4;
      int col = bn + wn + j*16 + r;
      const float* bp = (col < 512) ? b0 : (col < 1024) ? b1 : b2;
      float bias = bp[col & 511];
      #pragma unroll
      for (int g = 0; g < 4; g++)
        C[(size_t)(row + g)*N + col] = __float2bfloat16(acc[i][j][g] + bias);
    }
  }
}

// ---------------- logits MFMA: d_out[8192,17] = hbf @ WtLog^T + ofc_b (fp32 out) ----------------
__global__ __launch_bounds__(256)
void gemm_logits(const bf16* __restrict__ A, const bf16* __restrict__ Wt,
                 const float* __restrict__ bias, float* __restrict__ C){
  const int K = 512;
  __shared__ bf16 As[128*32];
  __shared__ bf16 Bs[128*32];
  int t = threadIdx.x;
  int wave = t >> 6, lane = t & 63;
  int bm = blockIdx.y * 128;
  int wm = (wave & 1) * 64, wn = (wave >> 1) * 64;
  ffrag acc[4][4];
  #pragma unroll
  for (int i = 0; i < 4; i++)
    #pragma unroll
    for (int j = 0; j < 4; j++) acc[i][j] = (ffrag){0.f,0.f,0.f,0.f};

  int srow = t >> 2;
  int scol = (t & 3) * 8;
  const bf16* gA = A  + (size_t)(bm + srow)*K + scol;
  const bf16* gB = Wt + (size_t)srow*K + scol;
  char* lA = (char*)As + 16*t;
  char* lB = (char*)Bs + 16*t;
  int q = lane >> 4, r = lane & 15;

  for (int k0 = 0; k0 < K; k0 += 32){
    gld16(gA + k0,          lA);
    gld16(gA + 64*K + k0,   lA + 4096);
    gld16(gB + k0,          lB);
    gld16(gB + 64*K + k0,   lB + 4096);
    __syncthreads();
    bfrag af[4], bfv[4];
    #pragma unroll
    for (int i = 0; i < 4; i++){
      af[i]  = *(const bfrag*)(As + (wm + i*16 + r)*32 + q*8);
      bfv[i] = *(const bfrag*)(Bs + (wn + i*16 + r)*32 + q*8);
    }
    #pragma unroll
    for (int i = 0; i < 4; i++)
      #pragma unroll
      for (int j = 0; j < 4; j++)
        acc[i][j] = __builtin_amdgcn_mfma_f32_16x16x32_bf16(af[i], bfv[j], acc[i][j], 0, 0, 0);
    __syncthreads();
  }
  #pragma unroll
  for (int i = 0; i < 4; i++){
    #pragma unroll
    for (int j = 0; j < 4; j++){
      int row = bm + wm + i*16 + q*4;
      int col = wn + j*16 + r;
      if (col < TT){
        float bias_v = bias[col];
        #pragma unroll
        for (int g = 0; g < 4; g++)
          C[(size_t)(row + g)*TT + col] = acc[i][j][g] + bias_v;
      }
    }
  }
}

// ---------------- batched s-projections: 8-way split-k, 32-col chunks (fp32) ----------------
__global__ __launch_bounds__(256)
void s_proj(const float* __restrict__ A,
            const float* __restrict__ W0, const float* __restrict__ W1,
            const float* __restrict__ W2, const float* __restrict__ W3,
            const float* __restrict__ W4,
            const float* __restrict__ bias0, const float* __restrict__ bias1,
            const float* __restrict__ bias2, const float* __restrict__ bias3,
            const float* __restrict__ bias4,
            float* __restrict__ O0, float* __restrict__ O1,
            float* __restrict__ O2, float* __restrict__ O3,
            float* __restrict__ O4,
            int ldc0, int ldc1, int ldc2, int ldc3, int ldc4){
  __shared__ float part[8][32][17];
  int t = threadIdx.x;
  int n = t & 31, kg = t >> 5;
  int wi = blockIdx.x >> 4, ch = blockIdx.x & 15;
  const float* W  = (wi==0)?W0:(wi==1)?W1:(wi==2)?W2:(wi==3)?W3:W4;
  const float* bs = (wi==0)?bias0:(wi==1)?bias1:(wi==2)?bias2:(wi==3)?bias3:bias4;
  float* O  = (wi==0)?O0:(wi==1)?O1:(wi==2)?O2:(wi==3)?O3:O4;
  int ldc   = (wi==0)?ldc0:(wi==1)?ldc1:(wi==2)?ldc2:(wi==3)?ldc3:ldc4;
  int col = ch*32 + n;
  float acc[16];
  #pragma unroll
  for (int m = 0; m < 16; m++) acc[m] = 0.f;
  const float* Wp = W + (size_t)(kg*64)*512 + col;
  const float* Ap = A + kg*64;
  for (int k = 0; k < 64; k++){
    float w = Wp[(size_t)k*512];
    #pragma unroll
    for (int m = 0; m < 16; m++) acc[m] = fmaf(Ap[m*512 + k], w, acc[m]);
  }
  #pragma unroll
  for (int m = 0; m < 16; m++) part[kg][n][m] = acc[m];
  __syncthreads();
  for (int o = t; o < 512; o += 256){
    int m = o >> 5, nn = o & 31;
    float v = 0.f;
    #pragma unroll
    for (int g = 0; g < 8; g++) v += part[g][nn][m];
    O[(size_t)m*ldc + ch*32 + nn] = v + bs[ch*32 + nn];
  }
}

// ---------------- sat attention (bf16 q/k/v from big tensors; fp32 s-keys) ----------------
__global__ void sat_attn(const bf16* __restrict__ qkv, const bf16* __restrict__ KeVe,
                         const float* __restrict__ KsVs, bf16* __restrict__ ctx){
  int gw = blockIdx.x*(blockDim.x >> 6) + (threadIdx.x >> 6);
  int lane = threadIdx.x & 63;
  int hh = gw & (NHH-1);
  int t  = gw >> 3;
  int b = t >> 9, l = t & 511;
  int base = hh*HDD + lane;
  float qv = __bfloat162float(qkv[(size_t)t*1536 + base]);
  int t0 = (b << 9) | ((l + 1) & 511);
  int t2 = (b << 9) | (l == 0 ? 511 : 0);
  float k[5];
  k[0] = __bfloat162float(qkv [(size_t)t0*1536 + 512 + base]);
  k[1] = __bfloat162float(qkv [(size_t)t *1536 + 512 + base]);
  k[2] = __bfloat162float(qkv [(size_t)t2*1536 + 512 + base]);
  k[3] = __bfloat162float(KeVe[(size_t)t *1024 + base]);
  k[4] = KsVs[(size_t)b *1024 + base];
  float sc[5];
  #pragma unroll
  for (int j = 0; j < 5; j++){
    float v = qv * k[j];
    #pragma unroll
    for (int off = 32; off; off >>= 1) v += __shfl_xor(v, off, 64);
    sc[j] = v * 0.125f;
  }
  float m = fmaxf(fmaxf(fmaxf(sc[0],sc[1]), fmaxf(sc[2],sc[3])), sc[4]);
  float p[5], den = 0.f;
  #pragma unroll
  for (int j = 0; j < 5; j++){ p[j] = __expf(sc[j]-m); den += p[j]; }
  float inv = 1.0f/den;
  float v0 = __bfloat162float(qkv [(size_t)t0*1536 + 1024 + base]);
  float v1 = __bfloat162float(qkv [(size_t)t *1536 + 1024 + base]);
  float v2 = __bfloat162float(qkv [(size_t)t2*1536 + 1024 + base]);
  float v3 = __bfloat162float(KeVe[(size_t)t *1024 + 512 + base]);
  float v4 = KsVs[(size_t)b *1024 + 512 + base];
  float o = (p[0]*v0 + p[1]*v1 + p[2]*v2 + p[3]*v3 + p[4]*v4) * inv;
  ctx[(size_t)t*DD + base] = __float2bfloat16(o);
}

// ---------------- rel attention pass 1 (bf16 KV, fp32 s-row) ----------------
__global__ __launch_bounds__(256)
void rel_part(const float* __restrict__ q, const float* __restrict__ Ksr,
              const float* __restrict__ Vsr, const bf16* __restrict__ KV,
              float* __restrict__ pws){
  int ch = blockIdx.x, hh = blockIdx.y, b = blockIdx.z;
  int t = threadIdx.x;
  int base = hh * HDD;
  __shared__ __align__(16) float qs[64];
  __shared__ float sc[RCK];
  __shared__ float red[256];
  __shared__ float part[4][64];
  int j0 = ch * RCK;
  int nk = min(513 - j0, RCK);
  if (t < 64) qs[t] = q[(size_t)b*DD + base + t];
  __syncthreads();
  if (t < nk){
    int j = j0 + t;
    float a = 0.f;
    if (j == 0){
      const float* kr = Ksr + (size_t)b*DD + base;
      #pragma unroll
      for (int d = 0; d < 64; d += 4){
        float4 k4 = *(const float4*)(kr + d);
        float4 q4 = *(const float4*)(qs + d);
        a += q4.x*k4.x + q4.y*k4.y + q4.z*k4.z + q4.w*k4.w;
      }
    } else {
      const bf16* kr = KV + ((size_t)b*LL + j - 1)*1024 + base;
      #pragma unroll
      for (int d = 0; d < 64; d += 8){
        us8 k8 = *(const us8*)(kr + d);
        #pragma unroll
        for (int g = 0; g < 8; g++) a += qs[d+g] * us2f(k8[g]);
      }
    }
    sc[t] = a * 0.125f;
  }
  __syncthreads();
  red[t] = (t < nk) ? sc[t] : -1e30f; __syncthreads();
  for (int st = 128; st; st >>= 1){ if (t < st) red[t] = fmaxf(red[t], red[t+st]); __syncthreads(); }
  float m = red[0]; __syncthreads();
  if (t < nk) sc[t] = __expf(sc[t] - m);
  __syncthreads();
  red[t] = (t < nk) ? sc[t] : 0.f; __syncthreads();
  for (int st = 128; st; st >>= 1){ if (t < st) red[t] += red[t+st]; __syncthreads(); }
  float l = red[0];
  int d = t & 63, c2 = t >> 6;
  float a = 0.f;
  for (int j = c2; j < nk; j += 4){
    int gj = j0 + j;
    float vv = (gj == 0) ? Vsr[(size_t)b*DD + base + d]
                         : __bfloat162float(KV[((size_t)b*LL + gj - 1)*1024 + 512 + base + d]);
    a += sc[j] * vv;
  }
  part[c2][d] = a; __syncthreads();
  float* o = pws + (((size_t)(b*NHH + hh))*RCH + ch) * 66;
  if (t < 64) o[t] = part[0][t] + part[1][t] + part[2][t] + part[3][t];
  else if (t == 64) o[64] = m;
  else if (t == 65) o[65] = l;
}

// ---------------- rel attention pass 2: combine chunks ----------------
__global__ void rel_comb(const float* __restrict__ pws, float* __restrict__ ctx){
  int bh = blockIdx.x;    // 0..127
  int t = threadIdx.x;    // 64
  const float* p = pws + (size_t)bh*RCH*66;
  float M = -1e30f;
  #pragma unroll
  for (int c = 0; c < RCH; c++) M = fmaxf(M, p[c*66 + 64]);
  float den = 0.f, acc = 0.f;
  #pragma unroll
  for (int c = 0; c < RCH; c++){
    float w = __expf(p[c*66 + 64] - M);
    den += w * p[c*66 + 65];
    acc += w * p[c*66 + t];
  }
  int b = bh >> 3, hh = bh & 7;
  ctx[(size_t)b*DD + hh*HDD + t] = acc / den;
}

// ---------------- h path: y = ln(relu(x)), bf16 in -> bf16 out ----------------
__global__ void relu_ln_bf(const bf16* __restrict__ X, const float* __restrict__ w,
                           const float* __restrict__ bn, bf16* __restrict__ Ybf){
  int row = blockIdx.x;
  int tid = threadIdx.x; // 256
  __shared__ float red[256];
  const bf16* x = X + (size_t)row*DD;
  float v0 = fmaxf(__bfloat162float(x[tid]), 0.f);
  float v1 = fmaxf(__bfloat162float(x[tid+256]), 0.f);
  red[tid] = v0 + v1;
  __syncthreads();
  for (int st = 128; st; st >>= 1){ if (tid < st) red[tid] += red[tid+st]; __syncthreads(); }
  float u = red[0] * (1.0f/DD);
  __syncthreads();
  float d0 = v0 - u, d1 = v1 - u;
  red[tid] = d0*d0 + d1*d1;
  __syncthreads();
  for (int st = 128; st; st >>= 1){ if (tid < st) red[tid] += red[tid+st]; __syncthreads(); }
  float var = red[0] * (1.0f/DD);
  float inv = rsqrtf(var + 1e-12f);
  Ybf[(size_t)row*DD + tid]       = __float2bfloat16(w[tid]    *d0*inv + bn[tid]);
  Ybf[(size_t)row*DD + tid + 256] = __float2bfloat16(w[tid+256]*d1*inv + bn[tid+256]);
}

// ---------------- s path: y = ln(relu(x)), fp32 in -> fp32 out ----------------
__global__ void relu_ln_s(const float* __restrict__ X, const float* __restrict__ w,
                          const float* __restrict__ bn, float* __restrict__ Y){
  int row = blockIdx.x;
  int tid = threadIdx.x; // 256
  __shared__ float red[256];
  const float* x = X + (size_t)row*DD;
  float v0 = fmaxf(x[tid], 0.f), v1 = fmaxf(x[tid+256], 0.f);
  red[tid] = v0 + v1;
  __syncthreads();
  for (int st = 128; st; st >>= 1){ if (tid < st) red[tid] += red[tid+st]; __syncthreads(); }
  float u = red[0] * (1.0f/DD);
  __syncthreads();
  float d0 = v0 - u, d1 = v1 - u;
  red[tid] = d0*d0 + d1*d1;
  __syncthreads();
  for (int st = 128; st; st >>= 1){ if (tid < st) red[tid] += red[tid+st]; __syncthreads(); }
  float var = red[0] * (1.0f/DD);
  float inv = rsqrtf(var + 1e-12f);
  // s MUST be written — it feeds the next cycle (round-5 bug: skipping it = poison).
  Y[(size_t)row*DD + tid]       = w[tid]    *d0*inv + bn[tid];
  Y[(size_t)row*DD + tid + 256] = w[tid+256]*d1*inv + bn[tid+256];
}

extern "C" void kernel_launch(void* const* d_in, const int* in_sizes, int n_in,
                              void* d_out, int out_size, void* d_ws, size_t ws_size,
                              hipStream_t stream) {
  const int*   tokens  = (const int*)  d_in[0];
  const float* emb     = (const float*)d_in[4];
  const float* sat_qw  = (const float*)d_in[5];
  const float* sat_qb  = (const float*)d_in[6];
  const float* sat_kw  = (const float*)d_in[7];
  const float* sat_kb  = (const float*)d_in[8];
  const float* sat_vw  = (const float*)d_in[9];
  const float* sat_vb  = (const float*)d_in[10];
  const float* sat_ow  = (const float*)d_in[11];
  const float* sat_ob  = (const float*)d_in[12];
  const float* rel_qw  = (const float*)d_in[13];
  const float* rel_qb  = (const float*)d_in[14];
  const float* rel_kw  = (const float*)d_in[15];
  const float* rel_kb  = (const float*)d_in[16];
  const float* rel_vw  = (const float*)d_in[17];
  const float* rel_vb  = (const float*)d_in[18];
  const float* rel_ow  = (const float*)d_in[19];
  const float* rel_ob  = (const float*)d_in[20];
  const float* ln_sat_w= (const float*)d_in[21];
  const float* ln_sat_b= (const float*)d_in[22];
  const float* ln_rel_w= (const float*)d_in[23];
  const float* ln_rel_b= (const float*)d_in[24];
  const float* ofc_w   = (const float*)d_in[25];
  const float* ofc_b   = (const float*)d_in[26];

  char* p = (char*)d_ws;
  auto alloc = [&](size_t bytes) -> char* {
    char* r = p; p += (bytes + 255) & ~(size_t)255; return r;
  };
  const size_t BIGH = (size_t)MM*DD*2;          // 8 MB (bf16 M x 512)
  bf16*  ebf   = (bf16*) alloc(BIGH);           // e bf16; later reused as hbf
  bf16*  qkv   = (bf16*) alloc(3*BIGH);         // [M,1536] bf16; aliased: aout + kv
  bf16*  KeVe  = (bf16*) alloc(2*BIGH);         // [M,1024] bf16
  bf16*  ctxbf = (bf16*) alloc(BIGH);
  bf16*  WtSat = (bf16*) alloc((size_t)1536*512*2);
  bf16*  WtRel = (bf16*) alloc((size_t)1024*512*2);
  bf16*  WtO   = (bf16*) alloc((size_t)512*512*2);
  bf16*  WtLog = (bf16*) alloc((size_t)128*512*2);
  float* s     = (float*)alloc(BB*DD*4);
  float* KsVs  = (float*)alloc(BB*1024*4);
  float* qr    = (float*)alloc(BB*DD*4);
  float* Ksr   = (float*)alloc(BB*DD*4);
  float* Vsr   = (float*)alloc(BB*DD*4);
  float* cr    = (float*)alloc(BB*DD*4);
  float* rr    = (float*)alloc(BB*DD*4);
  float* pws   = (float*)alloc((size_t)BB*NHH*RCH*66*4);
  bf16*  hbf   = ebf;                           // reuse: e_bf dead after cycle-0 QKV+mean
  bf16*  aout  = qkv;                           // reuse: qkv dead after sat_attn
  bf16*  kv    = qkv + (size_t)MM*512;          // [M,1024] bf16 inside qkv region

  int total = MM*DD;

  embed_kernel<<<(total+255)/256, 256, 0, stream>>>(tokens, emb, ebf, total);
  mean_kernel<<<(BB*DD)/256, 256, 0, stream>>>(ebf, s);

  prep_w<<<dim3(16,16,6), dim3(32,8), 0, stream>>>(
      sat_qw, sat_kw, sat_vw, rel_kw, rel_vw, sat_ow,
      WtSat, WtSat + (size_t)512*512, WtSat + (size_t)1024*512,
      WtRel, WtRel + (size_t)512*512, WtO);
  pad_logw<<<256, 256, 0, stream>>>(ofc_w, WtLog);

  // Ke|Ve = e @ [sat_kw|sat_vw] (constant across cycles)
  gemm_mfma_bf<<<dim3(8,64), 256, 0, stream>>>(ebf, WtSat + (size_t)512*512,
                                               sat_kb, sat_vb, sat_vb, KeVe, 1024);

  for (int c = 0; c < 2; c++){
    const bf16* hc = (c == 0) ? ebf : hbf;
    gemm_mfma_bf<<<dim3(12,64), 256, 0, stream>>>(hc, WtSat, sat_qb, sat_kb, sat_vb, qkv, 1536);
    s_proj<<<80, 256, 0, stream>>>(s,
        sat_kw, sat_vw, rel_qw, rel_kw, rel_vw,
        sat_kb, sat_vb, rel_qb, rel_kb, rel_vb,
        KsVs, KsVs + 512, qr, Ksr, Vsr,
        1024, 1024, 512, 512, 512);
    sat_attn<<<MM*NHH/4, 256, 0, stream>>>(qkv, KeVe, KsVs, ctxbf);
    gemm_mfma_bf<<<dim3(4,64), 256, 0, stream>>>(ctxbf, WtO, sat_ob, sat_ob, sat_ob, aout, 512);
    relu_ln_bf<<<MM, 256, 0, stream>>>(aout, ln_sat_w, ln_sat_b, hbf);
    gemm_mfma_bf<<<dim3(8,64), 256, 0, stream>>>(hbf, WtRel, rel_kb, rel_vb, rel_vb, kv, 1024);
    rel_part<<<dim3(RCH, NHH, BB), 256, 0, stream>>>(qr, Ksr, Vsr, kv, pws);
    rel_comb<<<BB*NHH, 64, 0, stream>>>(pws, cr);
    s_proj<<<16, 256, 0, stream>>>(cr,
        rel_ow, rel_ow, rel_ow, rel_ow, rel_ow,
        rel_ob, rel_ob, rel_ob, rel_ob, rel_ob,
        rr, rr, rr, rr, rr,
        512, 512, 512, 512, 512);
    relu_ln_s<<<BB, 256, 0, stream>>>(rr, ln_rel_w, ln_rel_b, s);
  }

  gemm_logits<<<dim3(1,64), 256, 0, stream>>>(hbf, WtLog, ofc_b, (float*)d_out);
}